// Round 6
// baseline (430.069 us; speedup 1.0000x reference)
//
#include <hip/hip_runtime.h>

#define N_PTS 4096
#define KNBR 40
#define BATCH 4

typedef __attribute__((ext_vector_type(8))) short bf16x8;
typedef __attribute__((ext_vector_type(4))) float f32x4;

__device__ __forceinline__ float lrelu(float v) { return v > 0.0f ? v : 0.2f * v; }

__device__ __forceinline__ short bf16_rn(float f) {
    unsigned u = __float_as_uint(f);
    unsigned r = (u + 0x7FFFu + ((u >> 16) & 1u)) >> 16;
    return (short)r;
}
__device__ __forceinline__ float bf16f(short h) {
    return __uint_as_float(((unsigned)(unsigned short)h) << 16);
}
__device__ __forceinline__ unsigned packbf(float v) {
    short h = bf16_rn(v);
    float r = v - bf16f(h);
    short l = bf16_rn(r);
    return (((unsigned)(unsigned short)h) << 16) | (unsigned)(unsigned short)l;
}
// truncate-hi split: hi = trunc(v), lo = trunc(v - hi). err(hi+lo) ~ 2^-16|v|
__device__ __forceinline__ unsigned pack_trunc(float v) {
    unsigned u = __float_as_uint(v);
    unsigned hi = u & 0xFFFF0000u;
    float r = v - __uint_as_float(hi);
    return hi | (__float_as_uint(r) >> 16);
}
// order-preserving float<->uint (max of encodings == encoding of max); 0 encodes below -inf
__device__ __forceinline__ unsigned fenc(float v) {
    unsigned u = __float_as_uint(v);
    return (u & 0x80000000u) ? ~u : (u | 0x80000000u);
}
__device__ __forceinline__ float fdec(unsigned e) {
    unsigned u = (e & 0x80000000u) ? (e ^ 0x80000000u) : ~e;
    return __uint_as_float(u);
}

// ---------------- KNN: exact top-40, TWO queries/block via packed dual histogram ----------------
// R1-exact body (HW-verified 79-80 us; re-verified R4/R5) -- FROZEN except the blk0 grid-offset
// param, which splits the dispatch 4-ways so mid-pipeline kernels surface in the profiler's
// top-5 (observability; 2048 blocks = 8/CU = one full residency fill).
// hist[bin] = (count_q1 << 16) | count_q0 (counts <= 4096 -> no cross-half carry).
__global__ __launch_bounds__(256) void knn_kernel(const float* __restrict__ x, int* __restrict__ idxo, int blk0)
{
    const int t = threadIdx.x;
    const int pt0 = (blockIdx.x + blk0) * 2;
    const int b = pt0 >> 12, n0 = pt0 & 4095, n1 = n0 + 1;
    const float* xb = x + b * 3 * N_PTS;
    const int lane = t & 63, wv = t >> 6;

    __shared__ unsigned hist[4096];
    __shared__ unsigned wtot[4];
    __shared__ int sh[16];
    // candidate overlays (hist is dead after the boundary-bin scans)
    unsigned* cov0 = hist;                 // [1024]
    int*      cidx0 = (int*)(hist + 1024); // [1024]
    unsigned* cov1 = hist + 2048;          // [1024]
    int*      cidx1 = (int*)(hist + 3072); // [1024]

    const float q0x = xb[n0], q0y = xb[N_PTS + n0], q0z = xb[2 * N_PTS + n0];
    const float q1x = xb[n1], q1y = xb[N_PTS + n1], q1z = xb[2 * N_PTS + n1];
    const float cc0 = q0x * q0x + q0y * q0y + q0z * q0z;
    const float cc1 = q1x * q1x + q1y * q1y + q1z * q1z;

    unsigned ov0[16], ov1[16];
#pragma unroll
    for (int j = 0; j < 16; ++j) {
        int m = t + j * 256;
        float a0 = xb[m], a1 = xb[N_PTS + m], a2 = xb[2 * N_PTS + m];
        float aa = a0 * a0 + a1 * a1 + a2 * a2;
        float d0 = 2.0f * (q0x * a0 + q0y * a1 + q0z * a2) - cc0 - aa;
        float d1 = 2.0f * (q1x * a0 + q1y * a1 + q1z * a2) - cc1 - aa;
        unsigned u0 = __float_as_uint(d0);
        ov0[j] = (u0 & 0x80000000u) ? ~u0 : (u0 | 0x80000000u);
        unsigned u1 = __float_as_uint(d1);
        ov1[j] = (u1 & 0x80000000u) ? ~u1 : (u1 | 0x80000000u);
    }

#pragma unroll
    for (int j = 0; j < 16; ++j) hist[t + j * 256] = 0;
    if (t < 16) sh[t] = 0;
    __syncthreads();
#pragma unroll
    for (int j = 0; j < 16; ++j) {
        atomicAdd(&hist[ov0[j] >> 20], 1u);
        atomicAdd(&hist[ov1[j] >> 20], 0x10000u);
    }
    __syncthreads();

    unsigned cs = 0;
    {
        const int rot = (t >> 1) & 15;
#pragma unroll
        for (int q = 0; q < 16; ++q) cs += hist[t * 16 + ((q + rot) & 15)];
    }
    unsigned val = cs;   // packed suffix-scan: per-half sums <= 4096, no cross-half carry
#pragma unroll
    for (int off = 1; off < 64; off <<= 1) {
        unsigned o = __shfl_down(val, off, 64);
        if (lane + off < 64) val += o;
    }
    if (lane == 0) wtot[wv] = val;
    __syncthreads();
    unsigned above_w = 0;
    for (int q = wv + 1; q < 4; ++q) above_w += wtot[q];
    unsigned Sincl = val + above_w;
    unsigned excl = Sincl - cs;
    {
        unsigned e0 = excl & 0xFFFFu, S0 = Sincl & 0xFFFFu;
        if (e0 < KNBR && S0 >= KNBR) { sh[0] = t; sh[1] = (int)e0; }
        unsigned e1 = excl >> 16, S1 = Sincl >> 16;
        if (e1 < KNBR && S1 >= KNBR) { sh[8] = t; sh[9] = (int)e1; }
    }
    __syncthreads();
    if (t == 0) {   // q0 boundary-bin scan
        int tstar = sh[0];
        unsigned run = (unsigned)sh[1];
        int B1 = -1; unsigned hcnt = 0;
        for (int q = 15; q >= 0; --q) {
            unsigned h = hist[tstar * 16 + q] & 0xFFFFu;
            if (run + h >= KNBR) { B1 = tstar * 16 + q; hcnt = h; break; }
            run += h;
        }
        sh[0] = B1; sh[1] = (int)run;
        sh[7] = KNBR - (int)run;
        sh[2] = ((int)hcnt > KNBR - (int)run) ? 1 : 0;
    }
    if (t == 64) {  // q1 boundary-bin scan (separate wave -> runs in parallel with t==0)
        int tstar = sh[8];
        unsigned run = (unsigned)sh[9];
        int B1 = -1; unsigned hcnt = 0;
        for (int q = 15; q >= 0; --q) {
            unsigned h = hist[tstar * 16 + q] >> 16;
            if (run + h >= KNBR) { B1 = tstar * 16 + q; hcnt = h; break; }
            run += h;
        }
        sh[8] = B1; sh[9] = (int)run;
        sh[15] = KNBR - (int)run;
        sh[10] = ((int)hcnt > KNBR - (int)run) ? 1 : 0;
    }
    __syncthreads();
    const unsigned B1_0 = (unsigned)sh[0];
    const int needRef0 = sh[2];
    const int R1_0 = sh[7];
    const int nab0 = sh[1];
    const unsigned B1_1 = (unsigned)sh[8];
    const int needRef1 = sh[10];
    const int R1_1 = sh[15];
    const int nab1 = sh[9];

    // counters: sh[3]=out q0, sh[6]=cand q0, sh[11]=out q1, sh[14]=cand q1
#pragma unroll
    for (int j = 0; j < 16; ++j) {
        int gi = t + j * 256;
        unsigned bb0 = ov0[j] >> 20;
        if (bb0 > B1_0) { int p = atomicAdd(&sh[3], 1); idxo[pt0 * KNBR + p] = gi; }
        else if (bb0 == B1_0) {
            if (!needRef0) { int p = atomicAdd(&sh[3], 1); idxo[pt0 * KNBR + p] = gi; }
            else { int q = atomicAdd(&sh[6], 1); if (q < 1024) { cov0[q] = ov0[j]; cidx0[q] = gi; } }
        }
        unsigned bb1 = ov1[j] >> 20;
        if (bb1 > B1_1) { int p = atomicAdd(&sh[11], 1); idxo[(pt0 + 1) * KNBR + p] = gi; }
        else if (bb1 == B1_1) {
            if (!needRef1) { int p = atomicAdd(&sh[11], 1); idxo[(pt0 + 1) * KNBR + p] = gi; }
            else { int q = atomicAdd(&sh[14], 1); if (q < 1024) { cov1[q] = ov1[j]; cidx1[q] = gi; } }
        }
    }
    if (!(needRef0 | needRef1)) return;
    __syncthreads();
    if (needRef0) {
        const int C = sh[6] < 1024 ? sh[6] : 1024;
        for (int j = t; j < C; j += 256) {
            unsigned myv = cov0[j]; int myi = cidx0[j];
            int rank = 0;
            for (int q = 0; q < C; ++q) {
                unsigned v = cov0[q];
                rank += (v > myv || (v == myv && cidx0[q] < myi)) ? 1 : 0;
            }
            if (rank < R1_0) idxo[pt0 * KNBR + nab0 + rank] = myi;
        }
    }
    if (needRef1) {
        const int C = sh[14] < 1024 ? sh[14] : 1024;
        for (int j = t; j < C; j += 256) {
            unsigned myv = cov1[j]; int myi = cidx1[j];
            int rank = 0;
            for (int q = 0; q < C; ++q) {
                unsigned v = cov1[q];
                rank += (v > myv || (v == myv && cidx1[q] < myi)) ? 1 : 0;
            }
            if (rank < R1_1) idxo[(pt0 + 1) * KNBR + nab1 + rank] = myi;
        }
    }
}

// ---------------- Layer 1 via MFMA: conv1(6->64 VALU) + conv2(64->64 MFMA) + in-reg max, 2 pts/block --------
__global__ __launch_bounds__(256) void layer1_mfma_kernel(const float* __restrict__ x, const int* __restrict__ idx,
    const float* __restrict__ W1, const float* __restrict__ s1, const float* __restrict__ b1,
    const short* __restrict__ w2h, const short* __restrict__ w2l,
    const float* __restrict__ s2, const float* __restrict__ b2,
    unsigned* __restrict__ x1p)
{
    const int t = threadIdx.x;
    const int pt0 = blockIdx.x * 2;
    const int b = pt0 >> 12;
    const float* xb = x + b * 3 * N_PTS;
    const int lane = t & 63, w = t >> 6;
    const int cn = lane & 15, kg = lane >> 4;

    __shared__ int idxs[80];
    __shared__ float w1t[384];          // [6][64] transposed W1
    __shared__ float ctrv[2][64];
    __shared__ float nbrc[80][4];
    __shared__ float Abuf[5808];
    short* A_hi = (short*)Abuf;
    short* A_lo = A_hi + 80 * 72;

    if (t < 80) idxs[t] = idx[pt0 * KNBR + t];
    if (t < 64) {
#pragma unroll
        for (int j = 0; j < 6; ++j) w1t[j * 64 + t] = W1[t * 6 + j];
    }
    __syncthreads();
    if (t < 240) { int k = t / 3, j = t % 3; nbrc[k][j] = xb[j * N_PTS + idxs[k]]; }
    if (t < 128) {
        int p = t >> 6, o = t & 63;
        int n = (pt0 + p) & 4095;
        float cx = xb[n], cy = xb[N_PTS + n], cz = xb[2 * N_PTS + n];
        ctrv[p][o] = (w1t[192 + o] - w1t[o]) * cx + (w1t[256 + o] - w1t[64 + o]) * cy
                   + (w1t[320 + o] - w1t[128 + o]) * cz;
    }
    bf16x8 bh[2], bl[2];
#pragma unroll
    for (int kc = 0; kc < 2; ++kc) {
        int off = (w * 16 + cn) * 64 + kc * 32 + kg * 8;
        bh[kc] = *(const bf16x8*)(w2h + off);
        bl[kc] = *(const bf16x8*)(w2l + off);
    }
    __syncthreads();
    {
        const int o = t & 63;
        const float w0 = w1t[o], w1v = w1t[64 + o], w2v = w1t[128 + o];
        const float sv = s1[o], bv = b1[o];
        const float cv0 = ctrv[0][o], cv1 = ctrv[1][o];
#pragma unroll
        for (int r = 0; r < 20; ++r) {
            int k = (t >> 6) + r * 4;
            float v = w0 * nbrc[k][0] + w1v * nbrc[k][1] + w2v * nbrc[k][2] + (k >= KNBR ? cv1 : cv0);
            v = lrelu(v * sv + bv);
            unsigned u = __float_as_uint(v);
            unsigned hi = u & 0xFFFF0000u;
            A_hi[k * 72 + o] = (short)(u >> 16);
            float rr = v - __uint_as_float(hi);
            A_lo[k * 72 + o] = (short)(__float_as_uint(rr) >> 16);
        }
    }
    __syncthreads();
    f32x4 acc[5];
#pragma unroll
    for (int mt = 0; mt < 5; ++mt) {
        f32x4 a = {0.f, 0.f, 0.f, 0.f};
#pragma unroll
        for (int kc = 0; kc < 2; ++kc) {
            int ao = (mt * 16 + cn) * 72 + kc * 32 + kg * 8;
            bf16x8 ah = *(const bf16x8*)(A_hi + ao);
            bf16x8 al = *(const bf16x8*)(A_lo + ao);
            a = __builtin_amdgcn_mfma_f32_16x16x32_bf16(al, bh[kc], a, 0, 0, 0);
            a = __builtin_amdgcn_mfma_f32_16x16x32_bf16(ah, bl[kc], a, 0, 0, 0);
            a = __builtin_amdgcn_mfma_f32_16x16x32_bf16(ah, bh[kc], a, 0, 0, 0);
        }
        acc[mt] = a;
    }
    const int o1 = w * 16 + cn;
    const float sB = s2[o1], bB = b2[o1];
    float m0 = -1e30f, m1 = -1e30f;
#pragma unroll
    for (int mt = 0; mt < 5; ++mt)
#pragma unroll
        for (int reg = 0; reg < 4; ++reg) {
            int row = mt * 16 + kg * 4 + reg;
            float v = lrelu(acc[mt][reg] * sB + bB);
            if (row < KNBR) m0 = fmaxf(m0, v); else m1 = fmaxf(m1, v);
        }
    m0 = fmaxf(m0, __shfl_xor(m0, 16, 64));
    m0 = fmaxf(m0, __shfl_xor(m0, 32, 64));
    m1 = fmaxf(m1, __shfl_xor(m1, 16, 64));
    m1 = fmaxf(m1, __shfl_xor(m1, 32, 64));
    if (kg == 0) {
        x1p[pt0 * 64 + o1] = packbf(m0);
        x1p[(pt0 + 1) * 64 + o1] = packbf(m1);
    }
}

// ---------------- merged prep: all weight splits + ctr-weight transpose + g zero-init ----------------
__global__ __launch_bounds__(256) void prep_all(
    const float* __restrict__ W2, const float* __restrict__ W3,
    const float* __restrict__ W4, const float* __restrict__ W5,
    const float* __restrict__ W6, const float* __restrict__ W7,
    const float* __restrict__ W8, const float* __restrict__ W9,
    short* __restrict__ w2h, short* __restrict__ w2l,
    short* __restrict__ w3h, short* __restrict__ w3l,
    short* __restrict__ w4h, short* __restrict__ w4l,
    short* __restrict__ w5h, short* __restrict__ w5l,
    float* __restrict__ wdt3, float* __restrict__ wdt5,
    short* __restrict__ w6h, short* __restrict__ w6l,
    short* __restrict__ w7h, short* __restrict__ w7l,
    short* __restrict__ w8h, short* __restrict__ w8l,
    short* __restrict__ w9h, short* __restrict__ w9l,
    unsigned* __restrict__ gu)
{
    int e = blockIdx.x * 256 + threadIdx.x;
    if (e < 4096) {
        gu[e] = 0u;   // below every fenc() encoding; conv6 epilogue atomicMax fills it
        int o = e >> 6, i = e & 63;
        float a = W3[o * 128 + i];
        short h = bf16_rn(a);
        w3h[e] = h; w3l[e] = bf16_rn(a - bf16f(h));
        wdt3[i * 64 + o] = W3[o * 128 + 64 + i] - a;
        float c = W4[o * 64 + i];
        h = bf16_rn(c);
        w4h[e] = h; w4l[e] = bf16_rn(c - bf16f(h));
        float d = W5[o * 128 + i];
        h = bf16_rn(d);
        w5h[e] = h; w5l[e] = bf16_rn(d - bf16f(h));
        wdt5[i * 64 + o] = W5[o * 128 + 64 + i] - d;
        float e2 = W2[o * 64 + i];
        h = bf16_rn(e2);
        w2h[e] = h; w2l[e] = bf16_rn(e2 - bf16f(h));
    }
    {
        float v; short* dh; short* dl; int di;
        if (e < 196608) {
            v = W6[e]; dh = w6h; dl = w6l; di = e;
        } else if (e < 294912) {
            int ee = e - 196608;
            int o = ee / 192, k = ee - o * 192;
            v = W7[o * 1216 + 1024 + k]; dh = w7h; dl = w7l; di = ee;
        } else if (e < 425984) {
            int ee = e - 294912;
            v = W8[ee]; dh = w8h; dl = w8l; di = ee;
        } else if (e < 442368) {
            int ee = e - 425984;
            int o = ee >> 8, k = ee & 255;
            v = (o < 63) ? W9[o * 256 + k] : 0.0f;
            dh = w9h; dl = w9l; di = ee;
        } else return;
        short h = bf16_rn(v);
        dh[di] = h; dl[di] = bf16_rn(v - bf16f(h));
    }
}

// ---------------- Edge layers via MFMA (split-bf16), packed input, in-reg max, 2 points/block, M=80 --------
template<int HAS2>
__global__ __launch_bounds__(256) void edge_mfma_kernel(const unsigned* __restrict__ srcp, const int* __restrict__ idx,
    const short* __restrict__ wah, const short* __restrict__ wal, const float* __restrict__ wdt,
    const float* __restrict__ sa, const float* __restrict__ ba,
    const short* __restrict__ wbh, const short* __restrict__ wbl,
    const float* __restrict__ sb, const float* __restrict__ bb,
    unsigned* __restrict__ xpout)
{
    const int t = threadIdx.x;
    const int pt0 = blockIdx.x * 2;
    const int b = pt0 >> 12;
    const int lane = t & 63, w = t >> 6;
    const int cn = lane & 15, kg = lane >> 4;

    __shared__ int idxs[80];
    __shared__ float ctr1[2][64];
    __shared__ float part[2][2][64];
    __shared__ float Abuf[5808];
    short* A_hi = (short*)Abuf;
    short* A_lo = A_hi + 80 * 72;

    if (t < 80) idxs[t] = idx[pt0 * KNBR + t];
    if (t >= 128) {
        int p = (t >> 6) & 1; int i = t & 63;
        unsigned u = srcp[(pt0 + p) * 64 + i];
        ctr1[p][i] = bf16f((short)(u >> 16)) + bf16f((short)u);
    }
    __syncthreads();

    bf16x8 bh[2], bl[2];
#pragma unroll
    for (int kc = 0; kc < 2; ++kc) {
        int off = (w * 16 + cn) * 64 + kc * 32 + kg * 8;
        bh[kc] = *(const bf16x8*)(wah + off);
        bl[kc] = *(const bf16x8*)(wal + off);
    }

    // gather packed neighbors -> unpack to hi/lo LDS planes (2 shifts/elem)
    {
        const int r0 = t >> 4, c4 = (t & 15) * 4;
#pragma unroll
        for (int r = 0; r < 5; ++r) {
            int row = r * 16 + r0;
            uint4 v = *(const uint4*)(srcp + (size_t)(b * N_PTS + idxs[row]) * 64 + c4);
            short4 h, l;
            h.x = (short)(v.x >> 16); l.x = (short)v.x;
            h.y = (short)(v.y >> 16); l.y = (short)v.y;
            h.z = (short)(v.z >> 16); l.z = (short)v.z;
            h.w = (short)(v.w >> 16); l.w = (short)v.w;
            *(short4*)(A_hi + row * 72 + c4) = h;
            *(short4*)(A_lo + row * 72 + c4) = l;
        }
    }
    // ctrv partials across all 256 threads (32 FMAs each)
    {
        int p = t >> 7, half = (t >> 6) & 1, o = t & 63;
        const float* wp = wdt + half * 32 * 64 + o;
        float s = 0.0f;
#pragma unroll 8
        for (int i = 0; i < 32; ++i) s = fmaf(wp[i * 64], ctr1[p][half * 32 + i], s);
        part[p][half][o] = s;
    }
    __syncthreads();

    f32x4 acc[5];
#pragma unroll
    for (int mt = 0; mt < 5; ++mt) {
        f32x4 a = {0.f, 0.f, 0.f, 0.f};
#pragma unroll
        for (int kc = 0; kc < 2; ++kc) {
            int ao = (mt * 16 + cn) * 72 + kc * 32 + kg * 8;
            bf16x8 ah = *(const bf16x8*)(A_hi + ao);
            bf16x8 al = *(const bf16x8*)(A_lo + ao);
            a = __builtin_amdgcn_mfma_f32_16x16x32_bf16(al, bh[kc], a, 0, 0, 0);
            a = __builtin_amdgcn_mfma_f32_16x16x32_bf16(ah, bl[kc], a, 0, 0, 0);
            a = __builtin_amdgcn_mfma_f32_16x16x32_bf16(ah, bh[kc], a, 0, 0, 0);
        }
        acc[mt] = a;
    }

    const int o1 = w * 16 + cn;
    const float cv0 = part[0][0][o1] + part[0][1][o1];
    const float cv1 = part[1][0][o1] + part[1][1][o1];
    const float sA = sa[o1], bA = ba[o1];

    if (HAS2) {
        __syncthreads();   // all MFMA reads of A done before overwrite
#pragma unroll
        for (int mt = 0; mt < 5; ++mt) {
#pragma unroll
            for (int reg = 0; reg < 4; ++reg) {
                int row = mt * 16 + kg * 4 + reg;
                float v = lrelu((acc[mt][reg] + (row >= KNBR ? cv1 : cv0)) * sA + bA);
                unsigned u = __float_as_uint(v);
                unsigned hi = u & 0xFFFF0000u;
                A_hi[row * 72 + o1] = (short)(u >> 16);
                float rr = v - __uint_as_float(hi);
                A_lo[row * 72 + o1] = (short)(__float_as_uint(rr) >> 16);
            }
        }
        __syncthreads();
#pragma unroll
        for (int kc = 0; kc < 2; ++kc) {
            int off = (w * 16 + cn) * 64 + kc * 32 + kg * 8;
            bh[kc] = *(const bf16x8*)(wbh + off);
            bl[kc] = *(const bf16x8*)(wbl + off);
        }
#pragma unroll
        for (int mt = 0; mt < 5; ++mt) {
            f32x4 a = {0.f, 0.f, 0.f, 0.f};
#pragma unroll
            for (int kc = 0; kc < 2; ++kc) {
                int ao = (mt * 16 + cn) * 72 + kc * 32 + kg * 8;
                bf16x8 ah = *(const bf16x8*)(A_hi + ao);
                bf16x8 al = *(const bf16x8*)(A_lo + ao);
                a = __builtin_amdgcn_mfma_f32_16x16x32_bf16(al, bh[kc], a, 0, 0, 0);
                a = __builtin_amdgcn_mfma_f32_16x16x32_bf16(ah, bl[kc], a, 0, 0, 0);
                a = __builtin_amdgcn_mfma_f32_16x16x32_bf16(ah, bh[kc], a, 0, 0, 0);
            }
            acc[mt] = a;
        }
        const float sB = sb[o1], bB = bb[o1];
        float m0 = -1e30f, m1 = -1e30f;
#pragma unroll
        for (int mt = 0; mt < 5; ++mt)
#pragma unroll
            for (int reg = 0; reg < 4; ++reg) {
                int row = mt * 16 + kg * 4 + reg;
                float v = lrelu(acc[mt][reg] * sB + bB);
                if (row < KNBR) m0 = fmaxf(m0, v); else m1 = fmaxf(m1, v);
            }
        m0 = fmaxf(m0, __shfl_xor(m0, 16, 64));
        m0 = fmaxf(m0, __shfl_xor(m0, 32, 64));
        m1 = fmaxf(m1, __shfl_xor(m1, 16, 64));
        m1 = fmaxf(m1, __shfl_xor(m1, 32, 64));
        if (kg == 0) {
            xpout[pt0 * 64 + o1] = packbf(m0);
            xpout[(pt0 + 1) * 64 + o1] = packbf(m1);
        }
    } else {
        float m0 = -1e30f, m1 = -1e30f;
#pragma unroll
        for (int mt = 0; mt < 5; ++mt)
#pragma unroll
            for (int reg = 0; reg < 4; ++reg) {
                int row = mt * 16 + kg * 4 + reg;
                float v = lrelu((acc[mt][reg] + (row >= KNBR ? cv1 : cv0)) * sA + bA);
                if (row < KNBR) m0 = fmaxf(m0, v); else m1 = fmaxf(m1, v);
            }
        m0 = fmaxf(m0, __shfl_xor(m0, 16, 64));
        m0 = fmaxf(m0, __shfl_xor(m0, 32, 64));
        m1 = fmaxf(m1, __shfl_xor(m1, 16, 64));
        m1 = fmaxf(m1, __shfl_xor(m1, 32, 64));
        if (kg == 0) {
            xpout[pt0 * 64 + o1] = packbf(m0);
            xpout[(pt0 + 1) * 64 + o1] = packbf(m1);
        }
    }
}

// ---------------- Split-bf16 MFMA GEMM, fused epilogues ----------------
// MODE 0: conv6 (A=x123p K=192, lrelu, global col-max via atomicMax(fenc) -> gu)
// MODE 3: conv9 (A=h8p K=256, +b9, transposed fp32 store, col<63)
template<int MODE, int MT, int NT, int KD, int NTOT>
__global__ __launch_bounds__(256) void gemm_mfma(
    const unsigned* __restrict__ A0, const unsigned* __restrict__ A1, const unsigned* __restrict__ A2,
    const short* __restrict__ Bh, const short* __restrict__ Bl,
    const float* __restrict__ sv, const float* __restrict__ bvv,
    const float* __restrict__ extra, void* __restrict__ outp)
{
    const int t = threadIdx.x;
    const int w = t >> 6, lane = t & 63;
    const int cn = lane & 15, kg = lane >> 4;
    const int m0 = blockIdx.x * (MT * 16);
    const int n0 = blockIdx.y * (NT * 64);

    __shared__ __align__(16) short Abuf2[2 * MT * 16 * 40];
    short* A_hi = Abuf2;
    short* A_lo = Abuf2 + MT * 16 * 40;

    f32x4 acc[MT][NT];
#pragma unroll
    for (int mt = 0; mt < MT; ++mt)
#pragma unroll
        for (int nt = 0; nt < NT; ++nt) acc[mt][nt] = (f32x4){0.f, 0.f, 0.f, 0.f};

    for (int kc = 0; kc < KD / 32; ++kc) {
        {
            const int kq = (t & 7) * 4;
            const int r0 = t >> 3;
#pragma unroll
            for (int rr = 0; rr < (MT * 16) / 32; ++rr) {
                int row = r0 + rr * 32;
                int gk = kc * 32 + kq;
                uint4 v;
                if (MODE == 0) {
                    const unsigned* srcp = (gk < 64) ? A0 : ((gk < 128) ? A1 : A2);
                    v = *(const uint4*)(srcp + (size_t)(m0 + row) * 64 + (gk & 63));
                } else {
                    v = *(const uint4*)(A0 + (size_t)(m0 + row) * KD + gk);
                }
                short4 h, l;
                h.x = (short)(v.x >> 16); l.x = (short)v.x;
                h.y = (short)(v.y >> 16); l.y = (short)v.y;
                h.z = (short)(v.z >> 16); l.z = (short)v.z;
                h.w = (short)(v.w >> 16); l.w = (short)v.w;
                *(short4*)(A_hi + row * 40 + kq) = h;
                *(short4*)(A_lo + row * 40 + kq) = l;
            }
        }
        __syncthreads();
        bf16x8 bh[NT], bl[NT];
#pragma unroll
        for (int nt = 0; nt < NT; ++nt) {
            int col = n0 + (w * NT + nt) * 16 + cn;
            int boff = col * KD + kc * 32 + kg * 8;
            bh[nt] = *(const bf16x8*)(Bh + boff);
            bl[nt] = *(const bf16x8*)(Bl + boff);
        }
#pragma unroll
        for (int mt = 0; mt < MT; ++mt) {
            int ao = (mt * 16 + cn) * 40 + kg * 8;
            bf16x8 ah = *(const bf16x8*)(A_hi + ao);
            bf16x8 al = *(const bf16x8*)(A_lo + ao);
#pragma unroll
            for (int nt = 0; nt < NT; ++nt) {
                acc[mt][nt] = __builtin_amdgcn_mfma_f32_16x16x32_bf16(al, bh[nt], acc[mt][nt], 0, 0, 0);
                acc[mt][nt] = __builtin_amdgcn_mfma_f32_16x16x32_bf16(ah, bl[nt], acc[mt][nt], 0, 0, 0);
                acc[mt][nt] = __builtin_amdgcn_mfma_f32_16x16x32_bf16(ah, bh[nt], acc[mt][nt], 0, 0, 0);
            }
        }
        __syncthreads();
    }

    if (MODE == 0) {
        unsigned* gp = (unsigned*)outp;
        const int b = m0 >> 12;
#pragma unroll
        for (int nt = 0; nt < NT; ++nt) {
            int col = n0 + (w * NT + nt) * 16 + cn;
            float s = sv[col], bb = bvv[col];
            float mx = -1e30f;
#pragma unroll
            for (int mt = 0; mt < MT; ++mt)
#pragma unroll
                for (int r = 0; r < 4; ++r) mx = fmaxf(mx, lrelu(acc[mt][nt][r] * s + bb));
            mx = fmaxf(mx, __shfl_xor(mx, 16, 64));
            mx = fmaxf(mx, __shfl_xor(mx, 32, 64));
            if (kg == 0) atomicMax(&gp[b * NTOT + col], fenc(mx));
        }
    } else {
        float* of = (float*)outp;
        const int b = m0 >> 12;
        const int nrow0 = m0 & 4095;
        int col = w * 16 + cn;
        if (col < 63) {
            float bb = bvv[col];
#pragma unroll
            for (int mt = 0; mt < MT; ++mt) {
                float4 o4;
                o4.x = acc[mt][0][0] + bb; o4.y = acc[mt][0][1] + bb;
                o4.z = acc[mt][0][2] + bb; o4.w = acc[mt][0][3] + bb;
                *(float4*)(of + (size_t)(b * 63 + col) * N_PTS + nrow0 + mt * 16 + kg * 4) = o4;
            }
        }
    }
}

// ---------------- MODE 2-style GEMM (contiguous packed A), packed output via LDS transpose ----------------
template<int MODE, int MT, int NT, int KD, int NTOT>
__global__ __launch_bounds__(256) void gemm_mfma_t(
    const unsigned* __restrict__ A0,
    const short* __restrict__ Bh, const short* __restrict__ Bl,
    const float* __restrict__ sv, const float* __restrict__ bvv,
    const float* __restrict__ extra, unsigned* __restrict__ op)
{
    const int t = threadIdx.x;
    const int w = t >> 6, lane = t & 63;
    const int cn = lane & 15, kg = lane >> 4;
    const int m0 = blockIdx.x * (MT * 16);
    const int n0 = blockIdx.y * (NT * 64);

    __shared__ __align__(16) short Abuf2[2 * MT * 16 * 40 > 2 * 16 * 132 * 2 ? 2 * MT * 16 * 40 : 2 * 16 * 132 * 2];
    short* A_hi = Abuf2;
    short* A_lo = Abuf2 + MT * 16 * 40;

    f32x4 acc[MT][NT];
#pragma unroll
    for (int mt = 0; mt < MT; ++mt)
#pragma unroll
        for (int nt = 0; nt < NT; ++nt) acc[mt][nt] = (f32x4){0.f, 0.f, 0.f, 0.f};

    for (int kc = 0; kc < KD / 32; ++kc) {
        {
            const int kq = (t & 7) * 4;
            const int r0 = t >> 3;
#pragma unroll
            for (int rr = 0; rr < (MT * 16) / 32; ++rr) {
                int row = r0 + rr * 32;
                int gk = kc * 32 + kq;
                uint4 v = *(const uint4*)(A0 + (size_t)(m0 + row) * KD + gk);
                short4 h, l;
                h.x = (short)(v.x >> 16); l.x = (short)v.x;
                h.y = (short)(v.y >> 16); l.y = (short)v.y;
                h.z = (short)(v.z >> 16); l.z = (short)v.z;
                h.w = (short)(v.w >> 16); l.w = (short)v.w;
                *(short4*)(A_hi + row * 40 + kq) = h;
                *(short4*)(A_lo + row * 40 + kq) = l;
            }
        }
        __syncthreads();
        bf16x8 bh[NT], bl[NT];
#pragma unroll
        for (int nt = 0; nt < NT; ++nt) {
            int col = n0 + (w * NT + nt) * 16 + cn;
            int boff = col * KD + kc * 32 + kg * 8;
            bh[nt] = *(const bf16x8*)(Bh + boff);
            bl[nt] = *(const bf16x8*)(Bl + boff);
        }
#pragma unroll
        for (int mt = 0; mt < MT; ++mt) {
            int ao = (mt * 16 + cn) * 40 + kg * 8;
            bf16x8 ah = *(const bf16x8*)(A_hi + ao);
            bf16x8 al = *(const bf16x8*)(A_lo + ao);
#pragma unroll
            for (int nt = 0; nt < NT; ++nt) {
                acc[mt][nt] = __builtin_amdgcn_mfma_f32_16x16x32_bf16(al, bh[nt], acc[mt][nt], 0, 0, 0);
                acc[mt][nt] = __builtin_amdgcn_mfma_f32_16x16x32_bf16(ah, bl[nt], acc[mt][nt], 0, 0, 0);
                acc[mt][nt] = __builtin_amdgcn_mfma_f32_16x16x32_bf16(ah, bh[nt], acc[mt][nt], 0, 0, 0);
            }
        }
        __syncthreads();
    }

    unsigned* T = (unsigned*)Abuf2;
    const int b = m0 >> 12;
#pragma unroll
    for (int mt = 0; mt < MT; ++mt) {
#pragma unroll
        for (int nt = 0; nt < NT; ++nt) {
            int col = n0 + (w * NT + nt) * 16 + cn;
            float s = sv[col], bb = bvv[col];
            float cc = (MODE == 1) ? extra[b * 512 + col] : 0.0f;
#pragma unroll
            for (int r = 0; r < 4; ++r) {
                float v = lrelu((acc[mt][nt][r] + cc) * s + bb);
                T[(kg * 4 + r) * 132 + (w * NT + nt) * 16 + cn] = pack_trunc(v);
            }
        }
        __syncthreads();
        {
            int row = t >> 4, c0 = (t & 15) * 8;
            uint4 u0 = *(uint4*)(T + row * 132 + c0);
            uint4 u1 = *(uint4*)(T + row * 132 + c0 + 4);
            int grow = m0 + mt * 16 + row;
            *(uint4*)(op + (size_t)grow * NTOT + n0 + c0) = u0;
            *(uint4*)(op + (size_t)grow * NTOT + n0 + c0 + 4) = u1;
        }
        __syncthreads();
    }
}

// ---------------- MODE 1 GEMM (three packed x-arrays), +c7 epilogue, packed output ----------------
template<int MT, int NT, int KD, int NTOT>
__global__ __launch_bounds__(256) void gemm_mfma_c7(
    const unsigned* __restrict__ A0, const unsigned* __restrict__ A1, const unsigned* __restrict__ A2,
    const short* __restrict__ Bh, const short* __restrict__ Bl,
    const float* __restrict__ sv, const float* __restrict__ bvv,
    const float* __restrict__ extra, unsigned* __restrict__ op)
{
    const int t = threadIdx.x;
    const int w = t >> 6, lane = t & 63;
    const int cn = lane & 15, kg = lane >> 4;
    const int m0 = blockIdx.x * (MT * 16);
    const int n0 = blockIdx.y * (NT * 64);

    __shared__ __align__(16) short Abuf2[2 * MT * 16 * 40 > 2 * 16 * 132 * 2 ? 2 * MT * 16 * 40 : 2 * 16 * 132 * 2];
    short* A_hi = Abuf2;
    short* A_lo = Abuf2 + MT * 16 * 40;

    f32x4 acc[MT][NT];
#pragma unroll
    for (int mt = 0; mt < MT; ++mt)
#pragma unroll
        for (int nt = 0; nt < NT; ++nt) acc[mt][nt] = (f32x4){0.f, 0.f, 0.f, 0.f};

    for (int kc = 0; kc < KD / 32; ++kc) {
        {
            const int kq = (t & 7) * 4;
            const int r0 = t >> 3;
#pragma unroll
            for (int rr = 0; rr < (MT * 16) / 32; ++rr) {
                int row = r0 + rr * 32;
                int gk = kc * 32 + kq;
                const unsigned* srcp = (gk < 64) ? A0 : ((gk < 128) ? A1 : A2);
                uint4 v = *(const uint4*)(srcp + (size_t)(m0 + row) * 64 + (gk & 63));
                short4 h, l;
                h.x = (short)(v.x >> 16); l.x = (short)v.x;
                h.y = (short)(v.y >> 16); l.y = (short)v.y;
                h.z = (short)(v.z >> 16); l.z = (short)v.z;
                h.w = (short)(v.w >> 16); l.w = (short)v.w;
                *(short4*)(A_hi + row * 40 + kq) = h;
                *(short4*)(A_lo + row * 40 + kq) = l;
            }
        }
        __syncthreads();
        bf16x8 bh[NT], bl[NT];
#pragma unroll
        for (int nt = 0; nt < NT; ++nt) {
            int col = n0 + (w * NT + nt) * 16 + cn;
            int boff = col * KD + kc * 32 + kg * 8;
            bh[nt] = *(const bf16x8*)(Bh + boff);
            bl[nt] = *(const bf16x8*)(Bl + boff);
        }
#pragma unroll
        for (int mt = 0; mt < MT; ++mt) {
            int ao = (mt * 16 + cn) * 40 + kg * 8;
            bf16x8 ah = *(const bf16x8*)(A_hi + ao);
            bf16x8 al = *(const bf16x8*)(A_lo + ao);
#pragma unroll
            for (int nt = 0; nt < NT; ++nt) {
                acc[mt][nt] = __builtin_amdgcn_mfma_f32_16x16x32_bf16(al, bh[nt], acc[mt][nt], 0, 0, 0);
                acc[mt][nt] = __builtin_amdgcn_mfma_f32_16x16x32_bf16(ah, bl[nt], acc[mt][nt], 0, 0, 0);
                acc[mt][nt] = __builtin_amdgcn_mfma_f32_16x16x32_bf16(ah, bh[nt], acc[mt][nt], 0, 0, 0);
            }
        }
        __syncthreads();
    }

    unsigned* T = (unsigned*)Abuf2;
    const int b = m0 >> 12;
#pragma unroll
    for (int mt = 0; mt < MT; ++mt) {
#pragma unroll
        for (int nt = 0; nt < NT; ++nt) {
            int col = n0 + (w * NT + nt) * 16 + cn;
            float s = sv[col], bb = bvv[col];
            float cc = extra[b * 512 + col];
#pragma unroll
            for (int r = 0; r < 4; ++r) {
                float v = lrelu((acc[mt][nt][r] + cc) * s + bb);
                T[(kg * 4 + r) * 132 + (w * NT + nt) * 16 + cn] = pack_trunc(v);
            }
        }
        __syncthreads();
        {
            int row = t >> 4, c0 = (t & 15) * 8;
            uint4 u0 = *(uint4*)(T + row * 132 + c0);
            uint4 u1 = *(uint4*)(T + row * 132 + c0 + 4);
            int grow = m0 + mt * 16 + row;
            *(uint4*)(op + (size_t)grow * NTOT + n0 + c0) = u0;
            *(uint4*)(op + (size_t)grow * NTOT + n0 + c0 + 4) = u1;
        }
        __syncthreads();
    }
}

// c7 = W7[:, :1024] . g  — split-K x16 + 16-lane shuffle-reduce (128 blocks on the serial chain);
// g arrives fenc()-encoded from conv6's atomicMax epilogue, decode inline.
__global__ __launch_bounds__(256) void c7_kernel(const unsigned* __restrict__ g, const float* __restrict__ W7,
                                                 float* __restrict__ c7)
{
    int gid = blockIdx.x * 256 + threadIdx.x;   // 32768 = 2048 outputs x 16 k-chunks
    int oc = gid >> 4;          // 0..2047 : b*512 + o
    int kc = gid & 15;          // k-chunk of 64
    int b = oc >> 9, o = oc & 511;
    const unsigned* gb = g + b * 1024 + kc * 64;
    const float* wr = W7 + o * 1216 + kc * 64;
    float s = 0.0f;
#pragma unroll
    for (int i = 0; i < 64; i += 4) {
        float4 wv4 = *reinterpret_cast<const float4*>(&wr[i]);
        uint4  gv4 = *reinterpret_cast<const uint4*>(&gb[i]);
        s += wv4.x * fdec(gv4.x) + wv4.y * fdec(gv4.y)
           + wv4.z * fdec(gv4.z) + wv4.w * fdec(gv4.w);
    }
    s += __shfl_down(s, 8, 64);
    s += __shfl_down(s, 4, 64);
    s += __shfl_down(s, 2, 64);
    s += __shfl_down(s, 1, 64);
    if (kc == 0) c7[oc] = s;
}

extern "C" void kernel_launch(void* const* d_in, const int* in_sizes, int n_in,
                              void* d_out, int out_size, void* d_ws, size_t ws_size,
                              hipStream_t stream)
{
    const float* x  = (const float*)d_in[0];
    const float* W1 = (const float*)d_in[1];
    const float* s1 = (const float*)d_in[2];
    const float* b1 = (const float*)d_in[3];
    const float* W2 = (const float*)d_in[4];
    const float* s2 = (const float*)d_in[5];
    const float* b2 = (const float*)d_in[6];
    const float* W3 = (const float*)d_in[7];
    const float* s3 = (const float*)d_in[8];
    const float* b3 = (const float*)d_in[9];
    const float* W4 = (const float*)d_in[10];
    const float* s4 = (const float*)d_in[11];
    const float* b4 = (const float*)d_in[12];
    const float* W5 = (const float*)d_in[13];
    const float* s5 = (const float*)d_in[14];
    const float* b5 = (const float*)d_in[15];
    const float* W6 = (const float*)d_in[16];
    const float* s6 = (const float*)d_in[17];
    const float* b6 = (const float*)d_in[18];
    const float* W7 = (const float*)d_in[19];
    const float* s7 = (const float*)d_in[20];
    const float* b7 = (const float*)d_in[21];
    const float* W8 = (const float*)d_in[22];
    const float* s8 = (const float*)d_in[23];
    const float* b8 = (const float*)d_in[24];
    const float* W9 = (const float*)d_in[25];
    const float* b9 = (const float*)d_in[26];

    char* ws = (char*)d_ws;
    int*      idx   = (int*)(ws);                      // 2.62 MB
    unsigned* x1p   = (unsigned*)(ws + 15204352);
    unsigned* x2p   = (unsigned*)(ws + 19398656);
    unsigned* x3p   = (unsigned*)(ws + 23592960);
    unsigned* gu    = (unsigned*)(ws + 28311552);      // fenc-encoded global col-max (4096)
    float*    c7    = (float*)(ws + 28327936);
    short*    w3h   = (short*)(ws + 28336128);
    short*    w3l   = w3h + 4096;
    short*    w4h   = w3h + 8192;
    short*    w4l   = w3h + 12288;
    short*    w5h   = w3h + 16384;
    short*    w5l   = w3h + 20480;
    float*    wdt3  = (float*)(ws + 28385280);
    float*    wdt5  = (float*)(ws + 28401664);
    short*    w6h   = (short*)(ws + 28418048);
    short*    w6l   = (short*)(ws + 28811264);
    short*    w7h   = (short*)(ws + 29204480);
    short*    w7l   = (short*)(ws + 29401088);
    short*    w8h   = (short*)(ws + 29597696);
    short*    w8l   = (short*)(ws + 29859840);
    short*    w9h   = (short*)(ws + 30121984);
    short*    w9l   = (short*)(ws + 30154752);
    short*    w2h   = (short*)(ws + 30187520);
    short*    w2l   = (short*)(ws + 30195712);
    unsigned* h7p   = (unsigned*)(ws + 30408704);      // 33.55 MB -> ends 63963136
    unsigned* h8p   = (unsigned*)(ws);                 // aliases dead early buffers
    float*    outp  = (float*)d_out;

    // knn split 4-ways (2048 blocks = 8/CU each) purely for profiler observability of the
    // mid-pipeline kernels; body identical to the frozen R1 kernel.
    knn_kernel<<<2048, 256, 0, stream>>>(x, idx, 0);
    knn_kernel<<<2048, 256, 0, stream>>>(x, idx, 2048);
    knn_kernel<<<2048, 256, 0, stream>>>(x, idx, 4096);
    knn_kernel<<<2048, 256, 0, stream>>>(x, idx, 6144);
    prep_all<<<1728, 256, 0, stream>>>(W2, W3, W4, W5, W6, W7, W8, W9,
        w2h, w2l, w3h, w3l, w4h, w4l, w5h, w5l, wdt3, wdt5,
        w6h, w6l, w7h, w7l, w8h, w8l, w9h, w9l, gu);
    layer1_mfma_kernel<<<BATCH * N_PTS / 2, 256, 0, stream>>>(x, idx, W1, s1, b1, w2h, w2l, s2, b2, x1p);
    edge_mfma_kernel<1><<<BATCH * N_PTS / 2, 256, 0, stream>>>(x1p, idx, w3h, w3l, wdt3, s3, b3, w4h, w4l, s4, b4, x2p);
    edge_mfma_kernel<0><<<BATCH * N_PTS / 2, 256, 0, stream>>>(x2p, idx, w5h, w5l, wdt5, s5, b5, nullptr, nullptr, nullptr, nullptr, x3p);
    gemm_mfma<0, 8, 2, 192, 1024><<<dim3(128, 8), 256, 0, stream>>>(x1p, x2p, x3p, w6h, w6l, s6, b6, nullptr, gu);
    c7_kernel<<<128, 256, 0, stream>>>(gu, W7, c7);
    gemm_mfma_c7<8, 2, 192, 512><<<dim3(128, 4), 256, 0, stream>>>(x1p, x2p, x3p, w7h, w7l, s7, b7, c7, h7p);
    gemm_mfma_t<2, 4, 2, 512, 256><<<dim3(256, 2), 256, 0, stream>>>(h7p, w8h, w8l, s8, b8, nullptr, h8p);
    gemm_mfma<3, 4, 1, 256, 64><<<dim3(256, 1), 256, 0, stream>>>(h8p, nullptr, nullptr, w9h, w9l, nullptr, b9, nullptr, outp);
}

// Round 7
// 409.496 us; speedup vs baseline: 1.0502x; 1.0502x over previous
//
#include <hip/hip_runtime.h>

#define N_PTS 4096
#define KNBR 40
#define BATCH 4

typedef __attribute__((ext_vector_type(8))) short bf16x8;
typedef __attribute__((ext_vector_type(4))) float f32x4;

__device__ __forceinline__ float lrelu(float v) { return v > 0.0f ? v : 0.2f * v; }

__device__ __forceinline__ short bf16_rn(float f) {
    unsigned u = __float_as_uint(f);
    unsigned r = (u + 0x7FFFu + ((u >> 16) & 1u)) >> 16;
    return (short)r;
}
__device__ __forceinline__ float bf16f(short h) {
    return __uint_as_float(((unsigned)(unsigned short)h) << 16);
}
__device__ __forceinline__ unsigned packbf(float v) {
    short h = bf16_rn(v);
    float r = v - bf16f(h);
    short l = bf16_rn(r);
    return (((unsigned)(unsigned short)h) << 16) | (unsigned)(unsigned short)l;
}
// truncate-hi split: hi = trunc(v), lo = trunc(v - hi). err(hi+lo) ~ 2^-16|v|
__device__ __forceinline__ unsigned pack_trunc(float v) {
    unsigned u = __float_as_uint(v);
    unsigned hi = u & 0xFFFF0000u;
    float r = v - __uint_as_float(hi);
    return hi | (__float_as_uint(r) >> 16);
}
// order-preserving float<->uint (max of encodings == encoding of max); 0 encodes below -inf
__device__ __forceinline__ unsigned fenc(float v) {
    unsigned u = __float_as_uint(v);
    return (u & 0x80000000u) ? ~u : (u | 0x80000000u);
}
__device__ __forceinline__ float fdec(unsigned e) {
    unsigned u = (e & 0x80000000u) ? (e ^ 0x80000000u) : ~e;
    return __uint_as_float(u);
}

// ---------------- KNN: exact top-40, TWO queries/block via packed dual histogram ----------------
// R1-exact body (HW-verified 79-80 us; re-verified R4/R5). Single dispatch restored (R6's 4-way
// split cost ~24 us in tail-drain; observability harvested). FROZEN.
// hist[bin] = (count_q1 << 16) | count_q0 (counts <= 4096 -> no cross-half carry).
__global__ __launch_bounds__(256) void knn_kernel(const float* __restrict__ x, int* __restrict__ idxo)
{
    const int t = threadIdx.x;
    const int pt0 = blockIdx.x * 2;
    const int b = pt0 >> 12, n0 = pt0 & 4095, n1 = n0 + 1;
    const float* xb = x + b * 3 * N_PTS;
    const int lane = t & 63, wv = t >> 6;

    __shared__ unsigned hist[4096];
    __shared__ unsigned wtot[4];
    __shared__ int sh[16];
    // candidate overlays (hist is dead after the boundary-bin scans)
    unsigned* cov0 = hist;                 // [1024]
    int*      cidx0 = (int*)(hist + 1024); // [1024]
    unsigned* cov1 = hist + 2048;          // [1024]
    int*      cidx1 = (int*)(hist + 3072); // [1024]

    const float q0x = xb[n0], q0y = xb[N_PTS + n0], q0z = xb[2 * N_PTS + n0];
    const float q1x = xb[n1], q1y = xb[N_PTS + n1], q1z = xb[2 * N_PTS + n1];
    const float cc0 = q0x * q0x + q0y * q0y + q0z * q0z;
    const float cc1 = q1x * q1x + q1y * q1y + q1z * q1z;

    unsigned ov0[16], ov1[16];
#pragma unroll
    for (int j = 0; j < 16; ++j) {
        int m = t + j * 256;
        float a0 = xb[m], a1 = xb[N_PTS + m], a2 = xb[2 * N_PTS + m];
        float aa = a0 * a0 + a1 * a1 + a2 * a2;
        float d0 = 2.0f * (q0x * a0 + q0y * a1 + q0z * a2) - cc0 - aa;
        float d1 = 2.0f * (q1x * a0 + q1y * a1 + q1z * a2) - cc1 - aa;
        unsigned u0 = __float_as_uint(d0);
        ov0[j] = (u0 & 0x80000000u) ? ~u0 : (u0 | 0x80000000u);
        unsigned u1 = __float_as_uint(d1);
        ov1[j] = (u1 & 0x80000000u) ? ~u1 : (u1 | 0x80000000u);
    }

#pragma unroll
    for (int j = 0; j < 16; ++j) hist[t + j * 256] = 0;
    if (t < 16) sh[t] = 0;
    __syncthreads();
#pragma unroll
    for (int j = 0; j < 16; ++j) {
        atomicAdd(&hist[ov0[j] >> 20], 1u);
        atomicAdd(&hist[ov1[j] >> 20], 0x10000u);
    }
    __syncthreads();

    unsigned cs = 0;
    {
        const int rot = (t >> 1) & 15;
#pragma unroll
        for (int q = 0; q < 16; ++q) cs += hist[t * 16 + ((q + rot) & 15)];
    }
    unsigned val = cs;   // packed suffix-scan: per-half sums <= 4096, no cross-half carry
#pragma unroll
    for (int off = 1; off < 64; off <<= 1) {
        unsigned o = __shfl_down(val, off, 64);
        if (lane + off < 64) val += o;
    }
    if (lane == 0) wtot[wv] = val;
    __syncthreads();
    unsigned above_w = 0;
    for (int q = wv + 1; q < 4; ++q) above_w += wtot[q];
    unsigned Sincl = val + above_w;
    unsigned excl = Sincl - cs;
    {
        unsigned e0 = excl & 0xFFFFu, S0 = Sincl & 0xFFFFu;
        if (e0 < KNBR && S0 >= KNBR) { sh[0] = t; sh[1] = (int)e0; }
        unsigned e1 = excl >> 16, S1 = Sincl >> 16;
        if (e1 < KNBR && S1 >= KNBR) { sh[8] = t; sh[9] = (int)e1; }
    }
    __syncthreads();
    if (t == 0) {   // q0 boundary-bin scan
        int tstar = sh[0];
        unsigned run = (unsigned)sh[1];
        int B1 = -1; unsigned hcnt = 0;
        for (int q = 15; q >= 0; --q) {
            unsigned h = hist[tstar * 16 + q] & 0xFFFFu;
            if (run + h >= KNBR) { B1 = tstar * 16 + q; hcnt = h; break; }
            run += h;
        }
        sh[0] = B1; sh[1] = (int)run;
        sh[7] = KNBR - (int)run;
        sh[2] = ((int)hcnt > KNBR - (int)run) ? 1 : 0;
    }
    if (t == 64) {  // q1 boundary-bin scan (separate wave -> runs in parallel with t==0)
        int tstar = sh[8];
        unsigned run = (unsigned)sh[9];
        int B1 = -1; unsigned hcnt = 0;
        for (int q = 15; q >= 0; --q) {
            unsigned h = hist[tstar * 16 + q] >> 16;
            if (run + h >= KNBR) { B1 = tstar * 16 + q; hcnt = h; break; }
            run += h;
        }
        sh[8] = B1; sh[9] = (int)run;
        sh[15] = KNBR - (int)run;
        sh[10] = ((int)hcnt > KNBR - (int)run) ? 1 : 0;
    }
    __syncthreads();
    const unsigned B1_0 = (unsigned)sh[0];
    const int needRef0 = sh[2];
    const int R1_0 = sh[7];
    const int nab0 = sh[1];
    const unsigned B1_1 = (unsigned)sh[8];
    const int needRef1 = sh[10];
    const int R1_1 = sh[15];
    const int nab1 = sh[9];

    // counters: sh[3]=out q0, sh[6]=cand q0, sh[11]=out q1, sh[14]=cand q1
#pragma unroll
    for (int j = 0; j < 16; ++j) {
        int gi = t + j * 256;
        unsigned bb0 = ov0[j] >> 20;
        if (bb0 > B1_0) { int p = atomicAdd(&sh[3], 1); idxo[pt0 * KNBR + p] = gi; }
        else if (bb0 == B1_0) {
            if (!needRef0) { int p = atomicAdd(&sh[3], 1); idxo[pt0 * KNBR + p] = gi; }
            else { int q = atomicAdd(&sh[6], 1); if (q < 1024) { cov0[q] = ov0[j]; cidx0[q] = gi; } }
        }
        unsigned bb1 = ov1[j] >> 20;
        if (bb1 > B1_1) { int p = atomicAdd(&sh[11], 1); idxo[(pt0 + 1) * KNBR + p] = gi; }
        else if (bb1 == B1_1) {
            if (!needRef1) { int p = atomicAdd(&sh[11], 1); idxo[(pt0 + 1) * KNBR + p] = gi; }
            else { int q = atomicAdd(&sh[14], 1); if (q < 1024) { cov1[q] = ov1[j]; cidx1[q] = gi; } }
        }
    }
    if (!(needRef0 | needRef1)) return;
    __syncthreads();
    if (needRef0) {
        const int C = sh[6] < 1024 ? sh[6] : 1024;
        for (int j = t; j < C; j += 256) {
            unsigned myv = cov0[j]; int myi = cidx0[j];
            int rank = 0;
            for (int q = 0; q < C; ++q) {
                unsigned v = cov0[q];
                rank += (v > myv || (v == myv && cidx0[q] < myi)) ? 1 : 0;
            }
            if (rank < R1_0) idxo[pt0 * KNBR + nab0 + rank] = myi;
        }
    }
    if (needRef1) {
        const int C = sh[14] < 1024 ? sh[14] : 1024;
        for (int j = t; j < C; j += 256) {
            unsigned myv = cov1[j]; int myi = cidx1[j];
            int rank = 0;
            for (int q = 0; q < C; ++q) {
                unsigned v = cov1[q];
                rank += (v > myv || (v == myv && cidx1[q] < myi)) ? 1 : 0;
            }
            if (rank < R1_1) idxo[(pt0 + 1) * KNBR + nab1 + rank] = myi;
        }
    }
}

// ---------------- Layer 1 via MFMA: conv1(6->64 VALU) + conv2(64->64 MFMA) + in-reg max, 2 pts/block --------
__global__ __launch_bounds__(256) void layer1_mfma_kernel(const float* __restrict__ x, const int* __restrict__ idx,
    const float* __restrict__ W1, const float* __restrict__ s1, const float* __restrict__ b1,
    const short* __restrict__ w2h, const short* __restrict__ w2l,
    const float* __restrict__ s2, const float* __restrict__ b2,
    unsigned* __restrict__ x1p)
{
    const int t = threadIdx.x;
    const int pt0 = blockIdx.x * 2;
    const int b = pt0 >> 12;
    const float* xb = x + b * 3 * N_PTS;
    const int lane = t & 63, w = t >> 6;
    const int cn = lane & 15, kg = lane >> 4;

    __shared__ int idxs[80];
    __shared__ float w1t[384];          // [6][64] transposed W1
    __shared__ float ctrv[2][64];
    __shared__ float nbrc[80][4];
    __shared__ float Abuf[5808];
    short* A_hi = (short*)Abuf;
    short* A_lo = A_hi + 80 * 72;

    if (t < 80) idxs[t] = idx[pt0 * KNBR + t];
    if (t < 64) {
#pragma unroll
        for (int j = 0; j < 6; ++j) w1t[j * 64 + t] = W1[t * 6 + j];
    }
    __syncthreads();
    if (t < 240) { int k = t / 3, j = t % 3; nbrc[k][j] = xb[j * N_PTS + idxs[k]]; }
    if (t < 128) {
        int p = t >> 6, o = t & 63;
        int n = (pt0 + p) & 4095;
        float cx = xb[n], cy = xb[N_PTS + n], cz = xb[2 * N_PTS + n];
        ctrv[p][o] = (w1t[192 + o] - w1t[o]) * cx + (w1t[256 + o] - w1t[64 + o]) * cy
                   + (w1t[320 + o] - w1t[128 + o]) * cz;
    }
    bf16x8 bh[2], bl[2];
#pragma unroll
    for (int kc = 0; kc < 2; ++kc) {
        int off = (w * 16 + cn) * 64 + kc * 32 + kg * 8;
        bh[kc] = *(const bf16x8*)(w2h + off);
        bl[kc] = *(const bf16x8*)(w2l + off);
    }
    __syncthreads();
    {
        const int o = t & 63;
        const float w0 = w1t[o], w1v = w1t[64 + o], w2v = w1t[128 + o];
        const float sv = s1[o], bv = b1[o];
        const float cv0 = ctrv[0][o], cv1 = ctrv[1][o];
#pragma unroll
        for (int r = 0; r < 20; ++r) {
            int k = (t >> 6) + r * 4;
            float v = w0 * nbrc[k][0] + w1v * nbrc[k][1] + w2v * nbrc[k][2] + (k >= KNBR ? cv1 : cv0);
            v = lrelu(v * sv + bv);
            unsigned u = __float_as_uint(v);
            unsigned hi = u & 0xFFFF0000u;
            A_hi[k * 72 + o] = (short)(u >> 16);
            float rr = v - __uint_as_float(hi);
            A_lo[k * 72 + o] = (short)(__float_as_uint(rr) >> 16);
        }
    }
    __syncthreads();
    f32x4 acc[5];
#pragma unroll
    for (int mt = 0; mt < 5; ++mt) {
        f32x4 a = {0.f, 0.f, 0.f, 0.f};
#pragma unroll
        for (int kc = 0; kc < 2; ++kc) {
            int ao = (mt * 16 + cn) * 72 + kc * 32 + kg * 8;
            bf16x8 ah = *(const bf16x8*)(A_hi + ao);
            bf16x8 al = *(const bf16x8*)(A_lo + ao);
            a = __builtin_amdgcn_mfma_f32_16x16x32_bf16(al, bh[kc], a, 0, 0, 0);
            a = __builtin_amdgcn_mfma_f32_16x16x32_bf16(ah, bl[kc], a, 0, 0, 0);
            a = __builtin_amdgcn_mfma_f32_16x16x32_bf16(ah, bh[kc], a, 0, 0, 0);
        }
        acc[mt] = a;
    }
    const int o1 = w * 16 + cn;
    const float sB = s2[o1], bB = b2[o1];
    float m0 = -1e30f, m1 = -1e30f;
#pragma unroll
    for (int mt = 0; mt < 5; ++mt)
#pragma unroll
        for (int reg = 0; reg < 4; ++reg) {
            int row = mt * 16 + kg * 4 + reg;
            float v = lrelu(acc[mt][reg] * sB + bB);
            if (row < KNBR) m0 = fmaxf(m0, v); else m1 = fmaxf(m1, v);
        }
    m0 = fmaxf(m0, __shfl_xor(m0, 16, 64));
    m0 = fmaxf(m0, __shfl_xor(m0, 32, 64));
    m1 = fmaxf(m1, __shfl_xor(m1, 16, 64));
    m1 = fmaxf(m1, __shfl_xor(m1, 32, 64));
    if (kg == 0) {
        x1p[pt0 * 64 + o1] = packbf(m0);
        x1p[(pt0 + 1) * 64 + o1] = packbf(m1);
    }
}

// ---------------- merged prep: all weight splits + ctr-weight transpose + g zero-init ----------------
__global__ __launch_bounds__(256) void prep_all(
    const float* __restrict__ W2, const float* __restrict__ W3,
    const float* __restrict__ W4, const float* __restrict__ W5,
    const float* __restrict__ W6, const float* __restrict__ W7,
    const float* __restrict__ W8, const float* __restrict__ W9,
    short* __restrict__ w2h, short* __restrict__ w2l,
    short* __restrict__ w3h, short* __restrict__ w3l,
    short* __restrict__ w4h, short* __restrict__ w4l,
    short* __restrict__ w5h, short* __restrict__ w5l,
    float* __restrict__ wdt3, float* __restrict__ wdt5,
    short* __restrict__ w6h, short* __restrict__ w6l,
    short* __restrict__ w7h, short* __restrict__ w7l,
    short* __restrict__ w8h, short* __restrict__ w8l,
    short* __restrict__ w9h, short* __restrict__ w9l,
    unsigned* __restrict__ gu)
{
    int e = blockIdx.x * 256 + threadIdx.x;
    if (e < 4096) {
        gu[e] = 0u;   // below every fenc() encoding; conv6 epilogue atomicMax fills it
        int o = e >> 6, i = e & 63;
        float a = W3[o * 128 + i];
        short h = bf16_rn(a);
        w3h[e] = h; w3l[e] = bf16_rn(a - bf16f(h));
        wdt3[i * 64 + o] = W3[o * 128 + 64 + i] - a;
        float c = W4[o * 64 + i];
        h = bf16_rn(c);
        w4h[e] = h; w4l[e] = bf16_rn(c - bf16f(h));
        float d = W5[o * 128 + i];
        h = bf16_rn(d);
        w5h[e] = h; w5l[e] = bf16_rn(d - bf16f(h));
        wdt5[i * 64 + o] = W5[o * 128 + 64 + i] - d;
        float e2 = W2[o * 64 + i];
        h = bf16_rn(e2);
        w2h[e] = h; w2l[e] = bf16_rn(e2 - bf16f(h));
    }
    {
        float v; short* dh; short* dl; int di;
        if (e < 196608) {
            v = W6[e]; dh = w6h; dl = w6l; di = e;
        } else if (e < 294912) {
            int ee = e - 196608;
            int o = ee / 192, k = ee - o * 192;
            v = W7[o * 1216 + 1024 + k]; dh = w7h; dl = w7l; di = ee;
        } else if (e < 425984) {
            int ee = e - 294912;
            v = W8[ee]; dh = w8h; dl = w8l; di = ee;
        } else if (e < 442368) {
            int ee = e - 425984;
            int o = ee >> 8, k = ee & 255;
            v = (o < 63) ? W9[o * 256 + k] : 0.0f;
            dh = w9h; dl = w9l; di = ee;
        } else return;
        short h = bf16_rn(v);
        dh[di] = h; dl[di] = bf16_rn(v - bf16f(h));
    }
}

// ---------------- Edge layers via MFMA (split-bf16), packed input, in-reg max, 2 points/block, M=80 --------
// Only HAS2=1 (conv3+conv4) remains an edge kernel; conv5 is now dense y5 + gather-max (R7).
template<int HAS2>
__global__ __launch_bounds__(256) void edge_mfma_kernel(const unsigned* __restrict__ srcp, const int* __restrict__ idx,
    const short* __restrict__ wah, const short* __restrict__ wal, const float* __restrict__ wdt,
    const float* __restrict__ sa, const float* __restrict__ ba,
    const short* __restrict__ wbh, const short* __restrict__ wbl,
    const float* __restrict__ sb, const float* __restrict__ bb,
    unsigned* __restrict__ xpout)
{
    const int t = threadIdx.x;
    const int pt0 = blockIdx.x * 2;
    const int b = pt0 >> 12;
    const int lane = t & 63, w = t >> 6;
    const int cn = lane & 15, kg = lane >> 4;

    __shared__ int idxs[80];
    __shared__ float ctr1[2][64];
    __shared__ float part[2][2][64];
    __shared__ float Abuf[5808];
    short* A_hi = (short*)Abuf;
    short* A_lo = A_hi + 80 * 72;

    if (t < 80) idxs[t] = idx[pt0 * KNBR + t];
    if (t >= 128) {
        int p = (t >> 6) & 1; int i = t & 63;
        unsigned u = srcp[(pt0 + p) * 64 + i];
        ctr1[p][i] = bf16f((short)(u >> 16)) + bf16f((short)u);
    }
    __syncthreads();

    bf16x8 bh[2], bl[2];
#pragma unroll
    for (int kc = 0; kc < 2; ++kc) {
        int off = (w * 16 + cn) * 64 + kc * 32 + kg * 8;
        bh[kc] = *(const bf16x8*)(wah + off);
        bl[kc] = *(const bf16x8*)(wal + off);
    }

    // gather packed neighbors -> unpack to hi/lo LDS planes (2 shifts/elem)
    {
        const int r0 = t >> 4, c4 = (t & 15) * 4;
#pragma unroll
        for (int r = 0; r < 5; ++r) {
            int row = r * 16 + r0;
            uint4 v = *(const uint4*)(srcp + (size_t)(b * N_PTS + idxs[row]) * 64 + c4);
            short4 h, l;
            h.x = (short)(v.x >> 16); l.x = (short)v.x;
            h.y = (short)(v.y >> 16); l.y = (short)v.y;
            h.z = (short)(v.z >> 16); l.z = (short)v.z;
            h.w = (short)(v.w >> 16); l.w = (short)v.w;
            *(short4*)(A_hi + row * 72 + c4) = h;
            *(short4*)(A_lo + row * 72 + c4) = l;
        }
    }
    // ctrv partials across all 256 threads (32 FMAs each)
    {
        int p = t >> 7, half = (t >> 6) & 1, o = t & 63;
        const float* wp = wdt + half * 32 * 64 + o;
        float s = 0.0f;
#pragma unroll 8
        for (int i = 0; i < 32; ++i) s = fmaf(wp[i * 64], ctr1[p][half * 32 + i], s);
        part[p][half][o] = s;
    }
    __syncthreads();

    f32x4 acc[5];
#pragma unroll
    for (int mt = 0; mt < 5; ++mt) {
        f32x4 a = {0.f, 0.f, 0.f, 0.f};
#pragma unroll
        for (int kc = 0; kc < 2; ++kc) {
            int ao = (mt * 16 + cn) * 72 + kc * 32 + kg * 8;
            bf16x8 ah = *(const bf16x8*)(A_hi + ao);
            bf16x8 al = *(const bf16x8*)(A_lo + ao);
            a = __builtin_amdgcn_mfma_f32_16x16x32_bf16(al, bh[kc], a, 0, 0, 0);
            a = __builtin_amdgcn_mfma_f32_16x16x32_bf16(ah, bl[kc], a, 0, 0, 0);
            a = __builtin_amdgcn_mfma_f32_16x16x32_bf16(ah, bh[kc], a, 0, 0, 0);
        }
        acc[mt] = a;
    }

    const int o1 = w * 16 + cn;
    const float cv0 = part[0][0][o1] + part[0][1][o1];
    const float cv1 = part[1][0][o1] + part[1][1][o1];
    const float sA = sa[o1], bA = ba[o1];

    if (HAS2) {
        __syncthreads();   // all MFMA reads of A done before overwrite
#pragma unroll
        for (int mt = 0; mt < 5; ++mt) {
#pragma unroll
            for (int reg = 0; reg < 4; ++reg) {
                int row = mt * 16 + kg * 4 + reg;
                float v = lrelu((acc[mt][reg] + (row >= KNBR ? cv1 : cv0)) * sA + bA);
                unsigned u = __float_as_uint(v);
                unsigned hi = u & 0xFFFF0000u;
                A_hi[row * 72 + o1] = (short)(u >> 16);
                float rr = v - __uint_as_float(hi);
                A_lo[row * 72 + o1] = (short)(__float_as_uint(rr) >> 16);
            }
        }
        __syncthreads();
#pragma unroll
        for (int kc = 0; kc < 2; ++kc) {
            int off = (w * 16 + cn) * 64 + kc * 32 + kg * 8;
            bh[kc] = *(const bf16x8*)(wbh + off);
            bl[kc] = *(const bf16x8*)(wbl + off);
        }
#pragma unroll
        for (int mt = 0; mt < 5; ++mt) {
            f32x4 a = {0.f, 0.f, 0.f, 0.f};
#pragma unroll
            for (int kc = 0; kc < 2; ++kc) {
                int ao = (mt * 16 + cn) * 72 + kc * 32 + kg * 8;
                bf16x8 ah = *(const bf16x8*)(A_hi + ao);
                bf16x8 al = *(const bf16x8*)(A_lo + ao);
                a = __builtin_amdgcn_mfma_f32_16x16x32_bf16(al, bh[kc], a, 0, 0, 0);
                a = __builtin_amdgcn_mfma_f32_16x16x32_bf16(ah, bl[kc], a, 0, 0, 0);
                a = __builtin_amdgcn_mfma_f32_16x16x32_bf16(ah, bh[kc], a, 0, 0, 0);
            }
            acc[mt] = a;
        }
        const float sB = sb[o1], bB = bb[o1];
        float m0 = -1e30f, m1 = -1e30f;
#pragma unroll
        for (int mt = 0; mt < 5; ++mt)
#pragma unroll
            for (int reg = 0; reg < 4; ++reg) {
                int row = mt * 16 + kg * 4 + reg;
                float v = lrelu(acc[mt][reg] * sB + bB);
                if (row < KNBR) m0 = fmaxf(m0, v); else m1 = fmaxf(m1, v);
            }
        m0 = fmaxf(m0, __shfl_xor(m0, 16, 64));
        m0 = fmaxf(m0, __shfl_xor(m0, 32, 64));
        m1 = fmaxf(m1, __shfl_xor(m1, 16, 64));
        m1 = fmaxf(m1, __shfl_xor(m1, 32, 64));
        if (kg == 0) {
            xpout[pt0 * 64 + o1] = packbf(m0);
            xpout[(pt0 + 1) * 64 + o1] = packbf(m1);
        }
    } else {
        float m0 = -1e30f, m1 = -1e30f;
#pragma unroll
        for (int mt = 0; mt < 5; ++mt)
#pragma unroll
            for (int reg = 0; reg < 4; ++reg) {
                int row = mt * 16 + kg * 4 + reg;
                float v = lrelu((acc[mt][reg] + (row >= KNBR ? cv1 : cv0)) * sA + bA);
                if (row < KNBR) m0 = fmaxf(m0, v); else m1 = fmaxf(m1, v);
            }
        m0 = fmaxf(m0, __shfl_xor(m0, 16, 64));
        m0 = fmaxf(m0, __shfl_xor(m0, 32, 64));
        m1 = fmaxf(m1, __shfl_xor(m1, 16, 64));
        m1 = fmaxf(m1, __shfl_xor(m1, 32, 64));
        if (kg == 0) {
            xpout[pt0 * 64 + o1] = packbf(m0);
            xpout[(pt0 + 1) * 64 + o1] = packbf(m1);
        }
    }
}

// ---------------- dense y5 = W5a . x2  (16384 x 64, K=64), raw packed output ----------------
// conv5's neighbor term is linear before the lrelu, so it is computed ONCE per point here
// instead of once per edge in the 66-us edge kernel; gmax_kernel applies cv + BN + lrelu + max.
__global__ __launch_bounds__(256) void dense_w5a_kernel(const unsigned* __restrict__ x2p,
    const short* __restrict__ w5h, const short* __restrict__ w5l, unsigned* __restrict__ y5p)
{
    const int t = threadIdx.x;
    const int w = t >> 6, lane = t & 63;
    const int cn = lane & 15, kg = lane >> 4;
    const int m0 = blockIdx.x * 64;
    __shared__ __align__(16) short Abuf2[2 * 64 * 40];
    short* A_hi = Abuf2;
    short* A_lo = Abuf2 + 64 * 40;

    f32x4 acc[4];
#pragma unroll
    for (int mt = 0; mt < 4; ++mt) acc[mt] = (f32x4){0.f, 0.f, 0.f, 0.f};

    for (int kc = 0; kc < 2; ++kc) {
        {
            const int kq = (t & 7) * 4;
            const int r0 = t >> 3;
#pragma unroll
            for (int rr = 0; rr < 2; ++rr) {
                int row = r0 + rr * 32;
                int gk = kc * 32 + kq;
                uint4 v = *(const uint4*)(x2p + (size_t)(m0 + row) * 64 + gk);
                short4 h, l;
                h.x = (short)(v.x >> 16); l.x = (short)v.x;
                h.y = (short)(v.y >> 16); l.y = (short)v.y;
                h.z = (short)(v.z >> 16); l.z = (short)v.z;
                h.w = (short)(v.w >> 16); l.w = (short)v.w;
                *(short4*)(A_hi + row * 40 + kq) = h;
                *(short4*)(A_lo + row * 40 + kq) = l;
            }
        }
        __syncthreads();
        bf16x8 bh, bl;
        {
            int boff = (w * 16 + cn) * 64 + kc * 32 + kg * 8;
            bh = *(const bf16x8*)(w5h + boff);
            bl = *(const bf16x8*)(w5l + boff);
        }
#pragma unroll
        for (int mt = 0; mt < 4; ++mt) {
            int ao = (mt * 16 + cn) * 40 + kg * 8;
            bf16x8 ah = *(const bf16x8*)(A_hi + ao);
            bf16x8 al = *(const bf16x8*)(A_lo + ao);
            acc[mt] = __builtin_amdgcn_mfma_f32_16x16x32_bf16(al, bh, acc[mt], 0, 0, 0);
            acc[mt] = __builtin_amdgcn_mfma_f32_16x16x32_bf16(ah, bl, acc[mt], 0, 0, 0);
            acc[mt] = __builtin_amdgcn_mfma_f32_16x16x32_bf16(ah, bh, acc[mt], 0, 0, 0);
        }
        __syncthreads();
    }
    const int col = w * 16 + cn;
#pragma unroll
    for (int mt = 0; mt < 4; ++mt)
#pragma unroll
        for (int r = 0; r < 4; ++r)
            y5p[(size_t)(m0 + mt * 16 + kg * 4 + r) * 64 + col] = pack_trunc(acc[mt][r]);
}

// ---------------- gather-max (replaces edge<0>): x3[pt][o] = max_k lrelu((y5[idx]+cv)*s5+b5) ----
// 4 points/block, one wave per point, lane = channel. No LDS staging, no MFMA: 40 independent
// coalesced 256-B gathers from L2-resident y5p per point.
__global__ __launch_bounds__(256) void gmax_kernel(const unsigned* __restrict__ y5p,
    const unsigned* __restrict__ x2p, const int* __restrict__ idx,
    const float* __restrict__ wdt5, const float* __restrict__ s5, const float* __restrict__ b5,
    unsigned* __restrict__ x3p)
{
    const int t = threadIdx.x;
    const int o = t & 63, pl = t >> 6;
    const int pt = blockIdx.x * 4 + pl;
    const int b = pt >> 12;

    __shared__ float ctrs[4][64];
    __shared__ int idxs[4][KNBR];

    {
        unsigned u = x2p[(size_t)pt * 64 + o];
        ctrs[pl][o] = bf16f((short)(u >> 16)) + bf16f((short)u);
    }
    if (o < KNBR) idxs[pl][o] = idx[pt * KNBR + o];
    __syncthreads();

    float cv = 0.0f;
#pragma unroll 8
    for (int i = 0; i < 64; ++i) cv = fmaf(wdt5[i * 64 + o], ctrs[pl][i], cv);

    const float sv = s5[o], bv = b5[o];
    float m = -1e30f;
    const unsigned* yb = y5p + (size_t)b * N_PTS * 64;
#pragma unroll 8
    for (int k = 0; k < KNBR; ++k) {
        unsigned u = yb[(size_t)idxs[pl][k] * 64 + o];
        float v = bf16f((short)(u >> 16)) + bf16f((short)u);
        m = fmaxf(m, lrelu(fmaf(v + cv, sv, bv)));
    }
    x3p[(size_t)pt * 64 + o] = packbf(m);
}

// ---------------- Split-bf16 MFMA GEMM, fused epilogues ----------------
// MODE 0: conv6 (A=x123p K=192, lrelu, global col-max via atomicMax(fenc) -> gu)
// MODE 3: conv9 (A=h8p K=256, +b9, transposed fp32 store, col<63)
template<int MODE, int MT, int NT, int KD, int NTOT>
__global__ __launch_bounds__(256) void gemm_mfma(
    const unsigned* __restrict__ A0, const unsigned* __restrict__ A1, const unsigned* __restrict__ A2,
    const short* __restrict__ Bh, const short* __restrict__ Bl,
    const float* __restrict__ sv, const float* __restrict__ bvv,
    const float* __restrict__ extra, void* __restrict__ outp)
{
    const int t = threadIdx.x;
    const int w = t >> 6, lane = t & 63;
    const int cn = lane & 15, kg = lane >> 4;
    const int m0 = blockIdx.x * (MT * 16);
    const int n0 = blockIdx.y * (NT * 64);

    __shared__ __align__(16) short Abuf2[2 * MT * 16 * 40];
    short* A_hi = Abuf2;
    short* A_lo = Abuf2 + MT * 16 * 40;

    f32x4 acc[MT][NT];
#pragma unroll
    for (int mt = 0; mt < MT; ++mt)
#pragma unroll
        for (int nt = 0; nt < NT; ++nt) acc[mt][nt] = (f32x4){0.f, 0.f, 0.f, 0.f};

    for (int kc = 0; kc < KD / 32; ++kc) {
        {
            const int kq = (t & 7) * 4;
            const int r0 = t >> 3;
#pragma unroll
            for (int rr = 0; rr < (MT * 16) / 32; ++rr) {
                int row = r0 + rr * 32;
                int gk = kc * 32 + kq;
                uint4 v;
                if (MODE == 0) {
                    const unsigned* srcp = (gk < 64) ? A0 : ((gk < 128) ? A1 : A2);
                    v = *(const uint4*)(srcp + (size_t)(m0 + row) * 64 + (gk & 63));
                } else {
                    v = *(const uint4*)(A0 + (size_t)(m0 + row) * KD + gk);
                }
                short4 h, l;
                h.x = (short)(v.x >> 16); l.x = (short)v.x;
                h.y = (short)(v.y >> 16); l.y = (short)v.y;
                h.z = (short)(v.z >> 16); l.z = (short)v.z;
                h.w = (short)(v.w >> 16); l.w = (short)v.w;
                *(short4*)(A_hi + row * 40 + kq) = h;
                *(short4*)(A_lo + row * 40 + kq) = l;
            }
        }
        __syncthreads();
        bf16x8 bh[NT], bl[NT];
#pragma unroll
        for (int nt = 0; nt < NT; ++nt) {
            int col = n0 + (w * NT + nt) * 16 + cn;
            int boff = col * KD + kc * 32 + kg * 8;
            bh[nt] = *(const bf16x8*)(Bh + boff);
            bl[nt] = *(const bf16x8*)(Bl + boff);
        }
#pragma unroll
        for (int mt = 0; mt < MT; ++mt) {
            int ao = (mt * 16 + cn) * 40 + kg * 8;
            bf16x8 ah = *(const bf16x8*)(A_hi + ao);
            bf16x8 al = *(const bf16x8*)(A_lo + ao);
#pragma unroll
            for (int nt = 0; nt < NT; ++nt) {
                acc[mt][nt] = __builtin_amdgcn_mfma_f32_16x16x32_bf16(al, bh[nt], acc[mt][nt], 0, 0, 0);
                acc[mt][nt] = __builtin_amdgcn_mfma_f32_16x16x32_bf16(ah, bl[nt], acc[mt][nt], 0, 0, 0);
                acc[mt][nt] = __builtin_amdgcn_mfma_f32_16x16x32_bf16(ah, bh[nt], acc[mt][nt], 0, 0, 0);
            }
        }
        __syncthreads();
    }

    if (MODE == 0) {
        unsigned* gp = (unsigned*)outp;
        const int b = m0 >> 12;
#pragma unroll
        for (int nt = 0; nt < NT; ++nt) {
            int col = n0 + (w * NT + nt) * 16 + cn;
            float s = sv[col], bb = bvv[col];
            float mx = -1e30f;
#pragma unroll
            for (int mt = 0; mt < MT; ++mt)
#pragma unroll
                for (int r = 0; r < 4; ++r) mx = fmaxf(mx, lrelu(acc[mt][nt][r] * s + bb));
            mx = fmaxf(mx, __shfl_xor(mx, 16, 64));
            mx = fmaxf(mx, __shfl_xor(mx, 32, 64));
            if (kg == 0) atomicMax(&gp[b * NTOT + col], fenc(mx));
        }
    } else {
        float* of = (float*)outp;
        const int b = m0 >> 12;
        const int nrow0 = m0 & 4095;
        int col = w * 16 + cn;
        if (col < 63) {
            float bb = bvv[col];
#pragma unroll
            for (int mt = 0; mt < MT; ++mt) {
                float4 o4;
                o4.x = acc[mt][0][0] + bb; o4.y = acc[mt][0][1] + bb;
                o4.z = acc[mt][0][2] + bb; o4.w = acc[mt][0][3] + bb;
                *(float4*)(of + (size_t)(b * 63 + col) * N_PTS + nrow0 + mt * 16 + kg * 4) = o4;
            }
        }
    }
}

// ---------------- MODE 2-style GEMM (contiguous packed A), packed output via LDS transpose ----------------
template<int MODE, int MT, int NT, int KD, int NTOT>
__global__ __launch_bounds__(256) void gemm_mfma_t(
    const unsigned* __restrict__ A0,
    const short* __restrict__ Bh, const short* __restrict__ Bl,
    const float* __restrict__ sv, const float* __restrict__ bvv,
    const float* __restrict__ extra, unsigned* __restrict__ op)
{
    const int t = threadIdx.x;
    const int w = t >> 6, lane = t & 63;
    const int cn = lane & 15, kg = lane >> 4;
    const int m0 = blockIdx.x * (MT * 16);
    const int n0 = blockIdx.y * (NT * 64);

    __shared__ __align__(16) short Abuf2[2 * MT * 16 * 40 > 2 * 16 * 132 * 2 ? 2 * MT * 16 * 40 : 2 * 16 * 132 * 2];
    short* A_hi = Abuf2;
    short* A_lo = Abuf2 + MT * 16 * 40;

    f32x4 acc[MT][NT];
#pragma unroll
    for (int mt = 0; mt < MT; ++mt)
#pragma unroll
        for (int nt = 0; nt < NT; ++nt) acc[mt][nt] = (f32x4){0.f, 0.f, 0.f, 0.f};

    for (int kc = 0; kc < KD / 32; ++kc) {
        {
            const int kq = (t & 7) * 4;
            const int r0 = t >> 3;
#pragma unroll
            for (int rr = 0; rr < (MT * 16) / 32; ++rr) {
                int row = r0 + rr * 32;
                int gk = kc * 32 + kq;
                uint4 v = *(const uint4*)(A0 + (size_t)(m0 + row) * KD + gk);
                short4 h, l;
                h.x = (short)(v.x >> 16); l.x = (short)v.x;
                h.y = (short)(v.y >> 16); l.y = (short)v.y;
                h.z = (short)(v.z >> 16); l.z = (short)v.z;
                h.w = (short)(v.w >> 16); l.w = (short)v.w;
                *(short4*)(A_hi + row * 40 + kq) = h;
                *(short4*)(A_lo + row * 40 + kq) = l;
            }
        }
        __syncthreads();
        bf16x8 bh[NT], bl[NT];
#pragma unroll
        for (int nt = 0; nt < NT; ++nt) {
            int col = n0 + (w * NT + nt) * 16 + cn;
            int boff = col * KD + kc * 32 + kg * 8;
            bh[nt] = *(const bf16x8*)(Bh + boff);
            bl[nt] = *(const bf16x8*)(Bl + boff);
        }
#pragma unroll
        for (int mt = 0; mt < MT; ++mt) {
            int ao = (mt * 16 + cn) * 40 + kg * 8;
            bf16x8 ah = *(const bf16x8*)(A_hi + ao);
            bf16x8 al = *(const bf16x8*)(A_lo + ao);
#pragma unroll
            for (int nt = 0; nt < NT; ++nt) {
                acc[mt][nt] = __builtin_amdgcn_mfma_f32_16x16x32_bf16(al, bh[nt], acc[mt][nt], 0, 0, 0);
                acc[mt][nt] = __builtin_amdgcn_mfma_f32_16x16x32_bf16(ah, bl[nt], acc[mt][nt], 0, 0, 0);
                acc[mt][nt] = __builtin_amdgcn_mfma_f32_16x16x32_bf16(ah, bh[nt], acc[mt][nt], 0, 0, 0);
            }
        }
        __syncthreads();
    }

    unsigned* T = (unsigned*)Abuf2;
    const int b = m0 >> 12;
#pragma unroll
    for (int mt = 0; mt < MT; ++mt) {
#pragma unroll
        for (int nt = 0; nt < NT; ++nt) {
            int col = n0 + (w * NT + nt) * 16 + cn;
            float s = sv[col], bb = bvv[col];
            float cc = (MODE == 1) ? extra[b * 512 + col] : 0.0f;
#pragma unroll
            for (int r = 0; r < 4; ++r) {
                float v = lrelu((acc[mt][nt][r] + cc) * s + bb);
                T[(kg * 4 + r) * 132 + (w * NT + nt) * 16 + cn] = pack_trunc(v);
            }
        }
        __syncthreads();
        {
            int row = t >> 4, c0 = (t & 15) * 8;
            uint4 u0 = *(uint4*)(T + row * 132 + c0);
            uint4 u1 = *(uint4*)(T + row * 132 + c0 + 4);
            int grow = m0 + mt * 16 + row;
            *(uint4*)(op + (size_t)grow * NTOT + n0 + c0) = u0;
            *(uint4*)(op + (size_t)grow * NTOT + n0 + c0 + 4) = u1;
        }
        __syncthreads();
    }
}

// ---------------- MODE 1 GEMM (three packed x-arrays), +c7 epilogue, packed output ----------------
template<int MT, int NT, int KD, int NTOT>
__global__ __launch_bounds__(256) void gemm_mfma_c7(
    const unsigned* __restrict__ A0, const unsigned* __restrict__ A1, const unsigned* __restrict__ A2,
    const short* __restrict__ Bh, const short* __restrict__ Bl,
    const float* __restrict__ sv, const float* __restrict__ bvv,
    const float* __restrict__ extra, unsigned* __restrict__ op)
{
    const int t = threadIdx.x;
    const int w = t >> 6, lane = t & 63;
    const int cn = lane & 15, kg = lane >> 4;
    const int m0 = blockIdx.x * (MT * 16);
    const int n0 = blockIdx.y * (NT * 64);

    __shared__ __align__(16) short Abuf2[2 * MT * 16 * 40 > 2 * 16 * 132 * 2 ? 2 * MT * 16 * 40 : 2 * 16 * 132 * 2];
    short* A_hi = Abuf2;
    short* A_lo = Abuf2 + MT * 16 * 40;

    f32x4 acc[MT][NT];
#pragma unroll
    for (int mt = 0; mt < MT; ++mt)
#pragma unroll
        for (int nt = 0; nt < NT; ++nt) acc[mt][nt] = (f32x4){0.f, 0.f, 0.f, 0.f};

    for (int kc = 0; kc < KD / 32; ++kc) {
        {
            const int kq = (t & 7) * 4;
            const int r0 = t >> 3;
#pragma unroll
            for (int rr = 0; rr < (MT * 16) / 32; ++rr) {
                int row = r0 + rr * 32;
                int gk = kc * 32 + kq;
                const unsigned* srcp = (gk < 64) ? A0 : ((gk < 128) ? A1 : A2);
                uint4 v = *(const uint4*)(srcp + (size_t)(m0 + row) * 64 + (gk & 63));
                short4 h, l;
                h.x = (short)(v.x >> 16); l.x = (short)v.x;
                h.y = (short)(v.y >> 16); l.y = (short)v.y;
                h.z = (short)(v.z >> 16); l.z = (short)v.z;
                h.w = (short)(v.w >> 16); l.w = (short)v.w;
                *(short4*)(A_hi + row * 40 + kq) = h;
                *(short4*)(A_lo + row * 40 + kq) = l;
            }
        }
        __syncthreads();
        bf16x8 bh[NT], bl[NT];
#pragma unroll
        for (int nt = 0; nt < NT; ++nt) {
            int col = n0 + (w * NT + nt) * 16 + cn;
            int boff = col * KD + kc * 32 + kg * 8;
            bh[nt] = *(const bf16x8*)(Bh + boff);
            bl[nt] = *(const bf16x8*)(Bl + boff);
        }
#pragma unroll
        for (int mt = 0; mt < MT; ++mt) {
            int ao = (mt * 16 + cn) * 40 + kg * 8;
            bf16x8 ah = *(const bf16x8*)(A_hi + ao);
            bf16x8 al = *(const bf16x8*)(A_lo + ao);
#pragma unroll
            for (int nt = 0; nt < NT; ++nt) {
                acc[mt][nt] = __builtin_amdgcn_mfma_f32_16x16x32_bf16(al, bh[nt], acc[mt][nt], 0, 0, 0);
                acc[mt][nt] = __builtin_amdgcn_mfma_f32_16x16x32_bf16(ah, bl[nt], acc[mt][nt], 0, 0, 0);
                acc[mt][nt] = __builtin_amdgcn_mfma_f32_16x16x32_bf16(ah, bh[nt], acc[mt][nt], 0, 0, 0);
            }
        }
        __syncthreads();
    }

    unsigned* T = (unsigned*)Abuf2;
    const int b = m0 >> 12;
#pragma unroll
    for (int mt = 0; mt < MT; ++mt) {
#pragma unroll
        for (int nt = 0; nt < NT; ++nt) {
            int col = n0 + (w * NT + nt) * 16 + cn;
            float s = sv[col], bb = bvv[col];
            float cc = extra[b * 512 + col];
#pragma unroll
            for (int r = 0; r < 4; ++r) {
                float v = lrelu((acc[mt][nt][r] + cc) * s + bb);
                T[(kg * 4 + r) * 132 + (w * NT + nt) * 16 + cn] = pack_trunc(v);
            }
        }
        __syncthreads();
        {
            int row = t >> 4, c0 = (t & 15) * 8;
            uint4 u0 = *(uint4*)(T + row * 132 + c0);
            uint4 u1 = *(uint4*)(T + row * 132 + c0 + 4);
            int grow = m0 + mt * 16 + row;
            *(uint4*)(op + (size_t)grow * NTOT + n0 + c0) = u0;
            *(uint4*)(op + (size_t)grow * NTOT + n0 + c0 + 4) = u1;
        }
        __syncthreads();
    }
}

// c7 = W7[:, :1024] . g  — split-K x16 + 16-lane shuffle-reduce (128 blocks on the serial chain);
// g arrives fenc()-encoded from conv6's atomicMax epilogue, decode inline.
__global__ __launch_bounds__(256) void c7_kernel(const unsigned* __restrict__ g, const float* __restrict__ W7,
                                                 float* __restrict__ c7)
{
    int gid = blockIdx.x * 256 + threadIdx.x;   // 32768 = 2048 outputs x 16 k-chunks
    int oc = gid >> 4;          // 0..2047 : b*512 + o
    int kc = gid & 15;          // k-chunk of 64
    int b = oc >> 9, o = oc & 511;
    const unsigned* gb = g + b * 1024 + kc * 64;
    const float* wr = W7 + o * 1216 + kc * 64;
    float s = 0.0f;
#pragma unroll
    for (int i = 0; i < 64; i += 4) {
        float4 wv4 = *reinterpret_cast<const float4*>(&wr[i]);
        uint4  gv4 = *reinterpret_cast<const uint4*>(&gb[i]);
        s += wv4.x * fdec(gv4.x) + wv4.y * fdec(gv4.y)
           + wv4.z * fdec(gv4.z) + wv4.w * fdec(gv4.w);
    }
    s += __shfl_down(s, 8, 64);
    s += __shfl_down(s, 4, 64);
    s += __shfl_down(s, 2, 64);
    s += __shfl_down(s, 1, 64);
    if (kc == 0) c7[oc] = s;
}

extern "C" void kernel_launch(void* const* d_in, const int* in_sizes, int n_in,
                              void* d_out, int out_size, void* d_ws, size_t ws_size,
                              hipStream_t stream)
{
    const float* x  = (const float*)d_in[0];
    const float* W1 = (const float*)d_in[1];
    const float* s1 = (const float*)d_in[2];
    const float* b1 = (const float*)d_in[3];
    const float* W2 = (const float*)d_in[4];
    const float* s2 = (const float*)d_in[5];
    const float* b2 = (const float*)d_in[6];
    const float* W3 = (const float*)d_in[7];
    const float* s3 = (const float*)d_in[8];
    const float* b3 = (const float*)d_in[9];
    const float* W4 = (const float*)d_in[10];
    const float* s4 = (const float*)d_in[11];
    const float* b4 = (const float*)d_in[12];
    const float* W5 = (const float*)d_in[13];
    const float* s5 = (const float*)d_in[14];
    const float* b5 = (const float*)d_in[15];
    const float* W6 = (const float*)d_in[16];
    const float* s6 = (const float*)d_in[17];
    const float* b6 = (const float*)d_in[18];
    const float* W7 = (const float*)d_in[19];
    const float* s7 = (const float*)d_in[20];
    const float* b7 = (const float*)d_in[21];
    const float* W8 = (const float*)d_in[22];
    const float* s8 = (const float*)d_in[23];
    const float* b8 = (const float*)d_in[24];
    const float* W9 = (const float*)d_in[25];
    const float* b9 = (const float*)d_in[26];

    char* ws = (char*)d_ws;
    int*      idx   = (int*)(ws);                      // 2.62 MB
    unsigned* y5p   = (unsigned*)(ws + 4194304);       // 4 MB dense W5a.x2 (dead before conv8's h8p reuse)
    unsigned* x1p   = (unsigned*)(ws + 15204352);
    unsigned* x2p   = (unsigned*)(ws + 19398656);
    unsigned* x3p   = (unsigned*)(ws + 23592960);
    unsigned* gu    = (unsigned*)(ws + 28311552);      // fenc-encoded global col-max (4096)
    float*    c7    = (float*)(ws + 28327936);
    short*    w3h   = (short*)(ws + 28336128);
    short*    w3l   = w3h + 4096;
    short*    w4h   = w3h + 8192;
    short*    w4l   = w3h + 12288;
    short*    w5h   = w3h + 16384;
    short*    w5l   = w3h + 20480;
    float*    wdt3  = (float*)(ws + 28385280);
    float*    wdt5  = (float*)(ws + 28401664);
    short*    w6h   = (short*)(ws + 28418048);
    short*    w6l   = (short*)(ws + 28811264);
    short*    w7h   = (short*)(ws + 29204480);
    short*    w7l   = (short*)(ws + 29401088);
    short*    w8h   = (short*)(ws + 29597696);
    short*    w8l   = (short*)(ws + 29859840);
    short*    w9h   = (short*)(ws + 30121984);
    short*    w9l   = (short*)(ws + 30154752);
    short*    w2h   = (short*)(ws + 30187520);
    short*    w2l   = (short*)(ws + 30195712);
    unsigned* h7p   = (unsigned*)(ws + 30408704);      // 33.55 MB -> ends 63963136
    unsigned* h8p   = (unsigned*)(ws);                 // aliases dead early buffers (idx, y5p)
    float*    outp  = (float*)d_out;

    knn_kernel<<<BATCH * N_PTS / 2, 256, 0, stream>>>(x, idx);
    prep_all<<<1728, 256, 0, stream>>>(W2, W3, W4, W5, W6, W7, W8, W9,
        w2h, w2l, w3h, w3l, w4h, w4l, w5h, w5l, wdt3, wdt5,
        w6h, w6l, w7h, w7l, w8h, w8l, w9h, w9l, gu);
    layer1_mfma_kernel<<<BATCH * N_PTS / 2, 256, 0, stream>>>(x, idx, W1, s1, b1, w2h, w2l, s2, b2, x1p);
    edge_mfma_kernel<1><<<BATCH * N_PTS / 2, 256, 0, stream>>>(x1p, idx, w3h, w3l, wdt3, s3, b3, w4h, w4l, s4, b4, x2p);
    dense_w5a_kernel<<<BATCH * N_PTS / 64, 256, 0, stream>>>(x2p, w5h, w5l, y5p);
    gmax_kernel<<<BATCH * N_PTS / 4, 256, 0, stream>>>(y5p, x2p, idx, wdt5, s5, b5, x3p);
    gemm_mfma<0, 8, 2, 192, 1024><<<dim3(128, 8), 256, 0, stream>>>(x1p, x2p, x3p, w6h, w6l, s6, b6, nullptr, gu);
    c7_kernel<<<128, 256, 0, stream>>>(gu, W7, c7);
    gemm_mfma_c7<8, 2, 192, 512><<<dim3(128, 4), 256, 0, stream>>>(x1p, x2p, x3p, w7h, w7l, s7, b7, c7, h7p);
    gemm_mfma_t<2, 4, 2, 512, 256><<<dim3(256, 2), 256, 0, stream>>>(h7p, w8h, w8l, s8, b8, nullptr, h8p);
    gemm_mfma<3, 4, 1, 256, 64><<<dim3(256, 1), 256, 0, stream>>>(h8p, nullptr, nullptr, w9h, w9l, nullptr, b9, nullptr, outp);
}

// Round 8
// 402.047 us; speedup vs baseline: 1.0697x; 1.0185x over previous
//
#include <hip/hip_runtime.h>

#define N_PTS 4096
#define KNBR 40
#define BATCH 4

typedef __attribute__((ext_vector_type(8))) short bf16x8;
typedef __attribute__((ext_vector_type(4))) float f32x4;

__device__ __forceinline__ float lrelu(float v) { return v > 0.0f ? v : 0.2f * v; }

__device__ __forceinline__ short bf16_rn(float f) {
    unsigned u = __float_as_uint(f);
    unsigned r = (u + 0x7FFFu + ((u >> 16) & 1u)) >> 16;
    return (short)r;
}
__device__ __forceinline__ float bf16f(short h) {
    return __uint_as_float(((unsigned)(unsigned short)h) << 16);
}
__device__ __forceinline__ unsigned packbf(float v) {
    short h = bf16_rn(v);
    float r = v - bf16f(h);
    short l = bf16_rn(r);
    return (((unsigned)(unsigned short)h) << 16) | (unsigned)(unsigned short)l;
}
// truncate-hi split: hi = trunc(v), lo = trunc(v - hi). err(hi+lo) ~ 2^-16|v|
__device__ __forceinline__ unsigned pack_trunc(float v) {
    unsigned u = __float_as_uint(v);
    unsigned hi = u & 0xFFFF0000u;
    float r = v - __uint_as_float(hi);
    return hi | (__float_as_uint(r) >> 16);
}
// order-preserving float<->uint (max of encodings == encoding of max); 0 encodes below -inf
__device__ __forceinline__ unsigned fenc(float v) {
    unsigned u = __float_as_uint(v);
    return (u & 0x80000000u) ? ~u : (u | 0x80000000u);
}
__device__ __forceinline__ float fdec(unsigned e) {
    unsigned u = (e & 0x80000000u) ? (e ^ 0x80000000u) : ~e;
    return __uint_as_float(u);
}

// ---------------- KNN: exact top-40, TWO queries/block via packed dual histogram ----------------
// R1-exact body (HW-verified 79-80 us; re-verified R4/R5/R7). FROZEN: R2/R3 variants of the key
// formula / load batching / parallel scan all regressed (91.6 / 119.8 us); R6's 4-way dispatch
// split cost ~24 us tail-drain.
// hist[bin] = (count_q1 << 16) | count_q0 (counts <= 4096 -> no cross-half carry).
__global__ __launch_bounds__(256) void knn_kernel(const float* __restrict__ x, int* __restrict__ idxo)
{
    const int t = threadIdx.x;
    const int pt0 = blockIdx.x * 2;
    const int b = pt0 >> 12, n0 = pt0 & 4095, n1 = n0 + 1;
    const float* xb = x + b * 3 * N_PTS;
    const int lane = t & 63, wv = t >> 6;

    __shared__ unsigned hist[4096];
    __shared__ unsigned wtot[4];
    __shared__ int sh[16];
    // candidate overlays (hist is dead after the boundary-bin scans)
    unsigned* cov0 = hist;                 // [1024]
    int*      cidx0 = (int*)(hist + 1024); // [1024]
    unsigned* cov1 = hist + 2048;          // [1024]
    int*      cidx1 = (int*)(hist + 3072); // [1024]

    const float q0x = xb[n0], q0y = xb[N_PTS + n0], q0z = xb[2 * N_PTS + n0];
    const float q1x = xb[n1], q1y = xb[N_PTS + n1], q1z = xb[2 * N_PTS + n1];
    const float cc0 = q0x * q0x + q0y * q0y + q0z * q0z;
    const float cc1 = q1x * q1x + q1y * q1y + q1z * q1z;

    unsigned ov0[16], ov1[16];
#pragma unroll
    for (int j = 0; j < 16; ++j) {
        int m = t + j * 256;
        float a0 = xb[m], a1 = xb[N_PTS + m], a2 = xb[2 * N_PTS + m];
        float aa = a0 * a0 + a1 * a1 + a2 * a2;
        float d0 = 2.0f * (q0x * a0 + q0y * a1 + q0z * a2) - cc0 - aa;
        float d1 = 2.0f * (q1x * a0 + q1y * a1 + q1z * a2) - cc1 - aa;
        unsigned u0 = __float_as_uint(d0);
        ov0[j] = (u0 & 0x80000000u) ? ~u0 : (u0 | 0x80000000u);
        unsigned u1 = __float_as_uint(d1);
        ov1[j] = (u1 & 0x80000000u) ? ~u1 : (u1 | 0x80000000u);
    }

#pragma unroll
    for (int j = 0; j < 16; ++j) hist[t + j * 256] = 0;
    if (t < 16) sh[t] = 0;
    __syncthreads();
#pragma unroll
    for (int j = 0; j < 16; ++j) {
        atomicAdd(&hist[ov0[j] >> 20], 1u);
        atomicAdd(&hist[ov1[j] >> 20], 0x10000u);
    }
    __syncthreads();

    unsigned cs = 0;
    {
        const int rot = (t >> 1) & 15;
#pragma unroll
        for (int q = 0; q < 16; ++q) cs += hist[t * 16 + ((q + rot) & 15)];
    }
    unsigned val = cs;   // packed suffix-scan: per-half sums <= 4096, no cross-half carry
#pragma unroll
    for (int off = 1; off < 64; off <<= 1) {
        unsigned o = __shfl_down(val, off, 64);
        if (lane + off < 64) val += o;
    }
    if (lane == 0) wtot[wv] = val;
    __syncthreads();
    unsigned above_w = 0;
    for (int q = wv + 1; q < 4; ++q) above_w += wtot[q];
    unsigned Sincl = val + above_w;
    unsigned excl = Sincl - cs;
    {
        unsigned e0 = excl & 0xFFFFu, S0 = Sincl & 0xFFFFu;
        if (e0 < KNBR && S0 >= KNBR) { sh[0] = t; sh[1] = (int)e0; }
        unsigned e1 = excl >> 16, S1 = Sincl >> 16;
        if (e1 < KNBR && S1 >= KNBR) { sh[8] = t; sh[9] = (int)e1; }
    }
    __syncthreads();
    if (t == 0) {   // q0 boundary-bin scan
        int tstar = sh[0];
        unsigned run = (unsigned)sh[1];
        int B1 = -1; unsigned hcnt = 0;
        for (int q = 15; q >= 0; --q) {
            unsigned h = hist[tstar * 16 + q] & 0xFFFFu;
            if (run + h >= KNBR) { B1 = tstar * 16 + q; hcnt = h; break; }
            run += h;
        }
        sh[0] = B1; sh[1] = (int)run;
        sh[7] = KNBR - (int)run;
        sh[2] = ((int)hcnt > KNBR - (int)run) ? 1 : 0;
    }
    if (t == 64) {  // q1 boundary-bin scan (separate wave -> runs in parallel with t==0)
        int tstar = sh[8];
        unsigned run = (unsigned)sh[9];
        int B1 = -1; unsigned hcnt = 0;
        for (int q = 15; q >= 0; --q) {
            unsigned h = hist[tstar * 16 + q] >> 16;
            if (run + h >= KNBR) { B1 = tstar * 16 + q; hcnt = h; break; }
            run += h;
        }
        sh[8] = B1; sh[9] = (int)run;
        sh[15] = KNBR - (int)run;
        sh[10] = ((int)hcnt > KNBR - (int)run) ? 1 : 0;
    }
    __syncthreads();
    const unsigned B1_0 = (unsigned)sh[0];
    const int needRef0 = sh[2];
    const int R1_0 = sh[7];
    const int nab0 = sh[1];
    const unsigned B1_1 = (unsigned)sh[8];
    const int needRef1 = sh[10];
    const int R1_1 = sh[15];
    const int nab1 = sh[9];

    // counters: sh[3]=out q0, sh[6]=cand q0, sh[11]=out q1, sh[14]=cand q1
#pragma unroll
    for (int j = 0; j < 16; ++j) {
        int gi = t + j * 256;
        unsigned bb0 = ov0[j] >> 20;
        if (bb0 > B1_0) { int p = atomicAdd(&sh[3], 1); idxo[pt0 * KNBR + p] = gi; }
        else if (bb0 == B1_0) {
            if (!needRef0) { int p = atomicAdd(&sh[3], 1); idxo[pt0 * KNBR + p] = gi; }
            else { int q = atomicAdd(&sh[6], 1); if (q < 1024) { cov0[q] = ov0[j]; cidx0[q] = gi; } }
        }
        unsigned bb1 = ov1[j] >> 20;
        if (bb1 > B1_1) { int p = atomicAdd(&sh[11], 1); idxo[(pt0 + 1) * KNBR + p] = gi; }
        else if (bb1 == B1_1) {
            if (!needRef1) { int p = atomicAdd(&sh[11], 1); idxo[(pt0 + 1) * KNBR + p] = gi; }
            else { int q = atomicAdd(&sh[14], 1); if (q < 1024) { cov1[q] = ov1[j]; cidx1[q] = gi; } }
        }
    }
    if (!(needRef0 | needRef1)) return;
    __syncthreads();
    if (needRef0) {
        const int C = sh[6] < 1024 ? sh[6] : 1024;
        for (int j = t; j < C; j += 256) {
            unsigned myv = cov0[j]; int myi = cidx0[j];
            int rank = 0;
            for (int q = 0; q < C; ++q) {
                unsigned v = cov0[q];
                rank += (v > myv || (v == myv && cidx0[q] < myi)) ? 1 : 0;
            }
            if (rank < R1_0) idxo[pt0 * KNBR + nab0 + rank] = myi;
        }
    }
    if (needRef1) {
        const int C = sh[14] < 1024 ? sh[14] : 1024;
        for (int j = t; j < C; j += 256) {
            unsigned myv = cov1[j]; int myi = cidx1[j];
            int rank = 0;
            for (int q = 0; q < C; ++q) {
                unsigned v = cov1[q];
                rank += (v > myv || (v == myv && cidx1[q] < myi)) ? 1 : 0;
            }
            if (rank < R1_1) idxo[(pt0 + 1) * KNBR + nab1 + rank] = myi;
        }
    }
}

// ---------------- Layer 1 via MFMA: conv1(6->64 VALU) + conv2(64->64 MFMA) + in-reg max, 2 pts/block --------
__global__ __launch_bounds__(256) void layer1_mfma_kernel(const float* __restrict__ x, const int* __restrict__ idx,
    const float* __restrict__ W1, const float* __restrict__ s1, const float* __restrict__ b1,
    const short* __restrict__ w2h, const short* __restrict__ w2l,
    const float* __restrict__ s2, const float* __restrict__ b2,
    unsigned* __restrict__ x1p)
{
    const int t = threadIdx.x;
    const int pt0 = blockIdx.x * 2;
    const int b = pt0 >> 12;
    const float* xb = x + b * 3 * N_PTS;
    const int lane = t & 63, w = t >> 6;
    const int cn = lane & 15, kg = lane >> 4;

    __shared__ int idxs[80];
    __shared__ float w1t[384];          // [6][64] transposed W1
    __shared__ float ctrv[2][64];
    __shared__ float nbrc[80][4];
    __shared__ float Abuf[5808];
    short* A_hi = (short*)Abuf;
    short* A_lo = A_hi + 80 * 72;

    if (t < 80) idxs[t] = idx[pt0 * KNBR + t];
    if (t < 64) {
#pragma unroll
        for (int j = 0; j < 6; ++j) w1t[j * 64 + t] = W1[t * 6 + j];
    }
    __syncthreads();
    if (t < 240) { int k = t / 3, j = t % 3; nbrc[k][j] = xb[j * N_PTS + idxs[k]]; }
    if (t < 128) {
        int p = t >> 6, o = t & 63;
        int n = (pt0 + p) & 4095;
        float cx = xb[n], cy = xb[N_PTS + n], cz = xb[2 * N_PTS + n];
        ctrv[p][o] = (w1t[192 + o] - w1t[o]) * cx + (w1t[256 + o] - w1t[64 + o]) * cy
                   + (w1t[320 + o] - w1t[128 + o]) * cz;
    }
    bf16x8 bh[2], bl[2];
#pragma unroll
    for (int kc = 0; kc < 2; ++kc) {
        int off = (w * 16 + cn) * 64 + kc * 32 + kg * 8;
        bh[kc] = *(const bf16x8*)(w2h + off);
        bl[kc] = *(const bf16x8*)(w2l + off);
    }
    __syncthreads();
    {
        const int o = t & 63;
        const float w0 = w1t[o], w1v = w1t[64 + o], w2v = w1t[128 + o];
        const float sv = s1[o], bv = b1[o];
        const float cv0 = ctrv[0][o], cv1 = ctrv[1][o];
#pragma unroll
        for (int r = 0; r < 20; ++r) {
            int k = (t >> 6) + r * 4;
            float v = w0 * nbrc[k][0] + w1v * nbrc[k][1] + w2v * nbrc[k][2] + (k >= KNBR ? cv1 : cv0);
            v = lrelu(v * sv + bv);
            unsigned u = __float_as_uint(v);
            unsigned hi = u & 0xFFFF0000u;
            A_hi[k * 72 + o] = (short)(u >> 16);
            float rr = v - __uint_as_float(hi);
            A_lo[k * 72 + o] = (short)(__float_as_uint(rr) >> 16);
        }
    }
    __syncthreads();
    f32x4 acc[5];
#pragma unroll
    for (int mt = 0; mt < 5; ++mt) {
        f32x4 a = {0.f, 0.f, 0.f, 0.f};
#pragma unroll
        for (int kc = 0; kc < 2; ++kc) {
            int ao = (mt * 16 + cn) * 72 + kc * 32 + kg * 8;
            bf16x8 ah = *(const bf16x8*)(A_hi + ao);
            bf16x8 al = *(const bf16x8*)(A_lo + ao);
            a = __builtin_amdgcn_mfma_f32_16x16x32_bf16(al, bh[kc], a, 0, 0, 0);
            a = __builtin_amdgcn_mfma_f32_16x16x32_bf16(ah, bl[kc], a, 0, 0, 0);
            a = __builtin_amdgcn_mfma_f32_16x16x32_bf16(ah, bh[kc], a, 0, 0, 0);
        }
        acc[mt] = a;
    }
    const int o1 = w * 16 + cn;
    const float sB = s2[o1], bB = b2[o1];
    float m0 = -1e30f, m1 = -1e30f;
#pragma unroll
    for (int mt = 0; mt < 5; ++mt)
#pragma unroll
        for (int reg = 0; reg < 4; ++reg) {
            int row = mt * 16 + kg * 4 + reg;
            float v = lrelu(acc[mt][reg] * sB + bB);
            if (row < KNBR) m0 = fmaxf(m0, v); else m1 = fmaxf(m1, v);
        }
    m0 = fmaxf(m0, __shfl_xor(m0, 16, 64));
    m0 = fmaxf(m0, __shfl_xor(m0, 32, 64));
    m1 = fmaxf(m1, __shfl_xor(m1, 16, 64));
    m1 = fmaxf(m1, __shfl_xor(m1, 32, 64));
    if (kg == 0) {
        x1p[pt0 * 64 + o1] = packbf(m0);
        x1p[(pt0 + 1) * 64 + o1] = packbf(m1);
    }
}

// ---------------- merged prep: all weight splits + ctr-weight transpose + g zero-init ----------------
__global__ __launch_bounds__(256) void prep_all(
    const float* __restrict__ W2, const float* __restrict__ W3,
    const float* __restrict__ W4, const float* __restrict__ W5,
    const float* __restrict__ W6, const float* __restrict__ W7,
    const float* __restrict__ W8, const float* __restrict__ W9,
    short* __restrict__ w2h, short* __restrict__ w2l,
    short* __restrict__ w3h, short* __restrict__ w3l,
    short* __restrict__ w4h, short* __restrict__ w4l,
    short* __restrict__ w5h, short* __restrict__ w5l,
    float* __restrict__ wdt3, float* __restrict__ wdt5,
    short* __restrict__ w6h, short* __restrict__ w6l,
    short* __restrict__ w7h, short* __restrict__ w7l,
    short* __restrict__ w8h, short* __restrict__ w8l,
    short* __restrict__ w9h, short* __restrict__ w9l,
    unsigned* __restrict__ gu)
{
    int e = blockIdx.x * 256 + threadIdx.x;
    if (e < 4096) {
        gu[e] = 0u;   // below every fenc() encoding; conv6 epilogue atomicMax fills it
        int o = e >> 6, i = e & 63;
        float a = W3[o * 128 + i];
        short h = bf16_rn(a);
        w3h[e] = h; w3l[e] = bf16_rn(a - bf16f(h));
        wdt3[i * 64 + o] = W3[o * 128 + 64 + i] - a;
        float c = W4[o * 64 + i];
        h = bf16_rn(c);
        w4h[e] = h; w4l[e] = bf16_rn(c - bf16f(h));
        float d = W5[o * 128 + i];
        h = bf16_rn(d);
        w5h[e] = h; w5l[e] = bf16_rn(d - bf16f(h));
        wdt5[i * 64 + o] = W5[o * 128 + 64 + i] - d;
        float e2 = W2[o * 64 + i];
        h = bf16_rn(e2);
        w2h[e] = h; w2l[e] = bf16_rn(e2 - bf16f(h));
    }
    {
        float v; short* dh; short* dl; int di;
        if (e < 196608) {
            v = W6[e]; dh = w6h; dl = w6l; di = e;
        } else if (e < 294912) {
            int ee = e - 196608;
            int o = ee / 192, k = ee - o * 192;
            v = W7[o * 1216 + 1024 + k]; dh = w7h; dl = w7l; di = ee;
        } else if (e < 425984) {
            int ee = e - 294912;
            v = W8[ee]; dh = w8h; dl = w8l; di = ee;
        } else if (e < 442368) {
            int ee = e - 425984;
            int o = ee >> 8, k = ee & 255;
            v = (o < 63) ? W9[o * 256 + k] : 0.0f;
            dh = w9h; dl = w9l; di = ee;
        } else return;
        short h = bf16_rn(v);
        dh[di] = h; dl[di] = bf16_rn(v - bf16f(h));
    }
}

// ---------------- Edge layers via MFMA (split-bf16), packed input, in-reg max, 2 points/block, M=80 --------
// R7 note: replacing edge<0> with dense-y5 + gather-max was net-negative (+4 us) -- the cost is
// the per-edge data movement both forms share, not the MFMA/epilogue structure. Keep as-is.
template<int HAS2>
__global__ __launch_bounds__(256) void edge_mfma_kernel(const unsigned* __restrict__ srcp, const int* __restrict__ idx,
    const short* __restrict__ wah, const short* __restrict__ wal, const float* __restrict__ wdt,
    const float* __restrict__ sa, const float* __restrict__ ba,
    const short* __restrict__ wbh, const short* __restrict__ wbl,
    const float* __restrict__ sb, const float* __restrict__ bb,
    unsigned* __restrict__ xpout)
{
    const int t = threadIdx.x;
    const int pt0 = blockIdx.x * 2;
    const int b = pt0 >> 12;
    const int lane = t & 63, w = t >> 6;
    const int cn = lane & 15, kg = lane >> 4;

    __shared__ int idxs[80];
    __shared__ float ctr1[2][64];
    __shared__ float part[2][2][64];
    __shared__ float Abuf[5808];
    short* A_hi = (short*)Abuf;
    short* A_lo = A_hi + 80 * 72;

    if (t < 80) idxs[t] = idx[pt0 * KNBR + t];
    if (t >= 128) {
        int p = (t >> 6) & 1; int i = t & 63;
        unsigned u = srcp[(pt0 + p) * 64 + i];
        ctr1[p][i] = bf16f((short)(u >> 16)) + bf16f((short)u);
    }
    __syncthreads();

    bf16x8 bh[2], bl[2];
#pragma unroll
    for (int kc = 0; kc < 2; ++kc) {
        int off = (w * 16 + cn) * 64 + kc * 32 + kg * 8;
        bh[kc] = *(const bf16x8*)(wah + off);
        bl[kc] = *(const bf16x8*)(wal + off);
    }

    // gather packed neighbors -> unpack to hi/lo LDS planes (2 shifts/elem)
    {
        const int r0 = t >> 4, c4 = (t & 15) * 4;
#pragma unroll
        for (int r = 0; r < 5; ++r) {
            int row = r * 16 + r0;
            uint4 v = *(const uint4*)(srcp + (size_t)(b * N_PTS + idxs[row]) * 64 + c4);
            short4 h, l;
            h.x = (short)(v.x >> 16); l.x = (short)v.x;
            h.y = (short)(v.y >> 16); l.y = (short)v.y;
            h.z = (short)(v.z >> 16); l.z = (short)v.z;
            h.w = (short)(v.w >> 16); l.w = (short)v.w;
            *(short4*)(A_hi + row * 72 + c4) = h;
            *(short4*)(A_lo + row * 72 + c4) = l;
        }
    }
    // ctrv partials across all 256 threads (32 FMAs each)
    {
        int p = t >> 7, half = (t >> 6) & 1, o = t & 63;
        const float* wp = wdt + half * 32 * 64 + o;
        float s = 0.0f;
#pragma unroll 8
        for (int i = 0; i < 32; ++i) s = fmaf(wp[i * 64], ctr1[p][half * 32 + i], s);
        part[p][half][o] = s;
    }
    __syncthreads();

    f32x4 acc[5];
#pragma unroll
    for (int mt = 0; mt < 5; ++mt) {
        f32x4 a = {0.f, 0.f, 0.f, 0.f};
#pragma unroll
        for (int kc = 0; kc < 2; ++kc) {
            int ao = (mt * 16 + cn) * 72 + kc * 32 + kg * 8;
            bf16x8 ah = *(const bf16x8*)(A_hi + ao);
            bf16x8 al = *(const bf16x8*)(A_lo + ao);
            a = __builtin_amdgcn_mfma_f32_16x16x32_bf16(al, bh[kc], a, 0, 0, 0);
            a = __builtin_amdgcn_mfma_f32_16x16x32_bf16(ah, bl[kc], a, 0, 0, 0);
            a = __builtin_amdgcn_mfma_f32_16x16x32_bf16(ah, bh[kc], a, 0, 0, 0);
        }
        acc[mt] = a;
    }

    const int o1 = w * 16 + cn;
    const float cv0 = part[0][0][o1] + part[0][1][o1];
    const float cv1 = part[1][0][o1] + part[1][1][o1];
    const float sA = sa[o1], bA = ba[o1];

    if (HAS2) {
        __syncthreads();   // all MFMA reads of A done before overwrite
#pragma unroll
        for (int mt = 0; mt < 5; ++mt) {
#pragma unroll
            for (int reg = 0; reg < 4; ++reg) {
                int row = mt * 16 + kg * 4 + reg;
                float v = lrelu((acc[mt][reg] + (row >= KNBR ? cv1 : cv0)) * sA + bA);
                unsigned u = __float_as_uint(v);
                unsigned hi = u & 0xFFFF0000u;
                A_hi[row * 72 + o1] = (short)(u >> 16);
                float rr = v - __uint_as_float(hi);
                A_lo[row * 72 + o1] = (short)(__float_as_uint(rr) >> 16);
            }
        }
        __syncthreads();
#pragma unroll
        for (int kc = 0; kc < 2; ++kc) {
            int off = (w * 16 + cn) * 64 + kc * 32 + kg * 8;
            bh[kc] = *(const bf16x8*)(wbh + off);
            bl[kc] = *(const bf16x8*)(wbl + off);
        }
#pragma unroll
        for (int mt = 0; mt < 5; ++mt) {
            f32x4 a = {0.f, 0.f, 0.f, 0.f};
#pragma unroll
            for (int kc = 0; kc < 2; ++kc) {
                int ao = (mt * 16 + cn) * 72 + kc * 32 + kg * 8;
                bf16x8 ah = *(const bf16x8*)(A_hi + ao);
                bf16x8 al = *(const bf16x8*)(A_lo + ao);
                a = __builtin_amdgcn_mfma_f32_16x16x32_bf16(al, bh[kc], a, 0, 0, 0);
                a = __builtin_amdgcn_mfma_f32_16x16x32_bf16(ah, bl[kc], a, 0, 0, 0);
                a = __builtin_amdgcn_mfma_f32_16x16x32_bf16(ah, bh[kc], a, 0, 0, 0);
            }
            acc[mt] = a;
        }
        const float sB = sb[o1], bB = bb[o1];
        float m0 = -1e30f, m1 = -1e30f;
#pragma unroll
        for (int mt = 0; mt < 5; ++mt)
#pragma unroll
            for (int reg = 0; reg < 4; ++reg) {
                int row = mt * 16 + kg * 4 + reg;
                float v = lrelu(acc[mt][reg] * sB + bB);
                if (row < KNBR) m0 = fmaxf(m0, v); else m1 = fmaxf(m1, v);
            }
        m0 = fmaxf(m0, __shfl_xor(m0, 16, 64));
        m0 = fmaxf(m0, __shfl_xor(m0, 32, 64));
        m1 = fmaxf(m1, __shfl_xor(m1, 16, 64));
        m1 = fmaxf(m1, __shfl_xor(m1, 32, 64));
        if (kg == 0) {
            xpout[pt0 * 64 + o1] = packbf(m0);
            xpout[(pt0 + 1) * 64 + o1] = packbf(m1);
        }
    } else {
        float m0 = -1e30f, m1 = -1e30f;
#pragma unroll
        for (int mt = 0; mt < 5; ++mt)
#pragma unroll
            for (int reg = 0; reg < 4; ++reg) {
                int row = mt * 16 + kg * 4 + reg;
                float v = lrelu((acc[mt][reg] + (row >= KNBR ? cv1 : cv0)) * sA + bA);
                if (row < KNBR) m0 = fmaxf(m0, v); else m1 = fmaxf(m1, v);
            }
        m0 = fmaxf(m0, __shfl_xor(m0, 16, 64));
        m0 = fmaxf(m0, __shfl_xor(m0, 32, 64));
        m1 = fmaxf(m1, __shfl_xor(m1, 16, 64));
        m1 = fmaxf(m1, __shfl_xor(m1, 32, 64));
        if (kg == 0) {
            xpout[pt0 * 64 + o1] = packbf(m0);
            xpout[(pt0 + 1) * 64 + o1] = packbf(m1);
        }
    }
}

// ---------------- Split-bf16 MFMA GEMM, fused epilogues ----------------
// MODE 0: conv6 (A=x123p K=192, lrelu, global col-max via atomicMax(fenc) -> gu)
// MODE 3: conv9 (A=h8p K=256, +b9, transposed fp32 store, col<63)
template<int MODE, int MT, int NT, int KD, int NTOT>
__global__ __launch_bounds__(256) void gemm_mfma(
    const unsigned* __restrict__ A0, const unsigned* __restrict__ A1, const unsigned* __restrict__ A2,
    const short* __restrict__ Bh, const short* __restrict__ Bl,
    const float* __restrict__ sv, const float* __restrict__ bvv,
    const float* __restrict__ extra, void* __restrict__ outp)
{
    const int t = threadIdx.x;
    const int w = t >> 6, lane = t & 63;
    const int cn = lane & 15, kg = lane >> 4;
    const int m0 = blockIdx.x * (MT * 16);
    const int n0 = blockIdx.y * (NT * 64);

    __shared__ __align__(16) short Abuf2[2 * MT * 16 * 40];
    short* A_hi = Abuf2;
    short* A_lo = Abuf2 + MT * 16 * 40;

    f32x4 acc[MT][NT];
#pragma unroll
    for (int mt = 0; mt < MT; ++mt)
#pragma unroll
        for (int nt = 0; nt < NT; ++nt) acc[mt][nt] = (f32x4){0.f, 0.f, 0.f, 0.f};

    for (int kc = 0; kc < KD / 32; ++kc) {
        {
            const int kq = (t & 7) * 4;
            const int r0 = t >> 3;
#pragma unroll
            for (int rr = 0; rr < (MT * 16) / 32; ++rr) {
                int row = r0 + rr * 32;
                int gk = kc * 32 + kq;
                uint4 v;
                if (MODE == 0) {
                    const unsigned* srcp = (gk < 64) ? A0 : ((gk < 128) ? A1 : A2);
                    v = *(const uint4*)(srcp + (size_t)(m0 + row) * 64 + (gk & 63));
                } else {
                    v = *(const uint4*)(A0 + (size_t)(m0 + row) * KD + gk);
                }
                short4 h, l;
                h.x = (short)(v.x >> 16); l.x = (short)v.x;
                h.y = (short)(v.y >> 16); l.y = (short)v.y;
                h.z = (short)(v.z >> 16); l.z = (short)v.z;
                h.w = (short)(v.w >> 16); l.w = (short)v.w;
                *(short4*)(A_hi + row * 40 + kq) = h;
                *(short4*)(A_lo + row * 40 + kq) = l;
            }
        }
        __syncthreads();
        bf16x8 bh[NT], bl[NT];
#pragma unroll
        for (int nt = 0; nt < NT; ++nt) {
            int col = n0 + (w * NT + nt) * 16 + cn;
            int boff = col * KD + kc * 32 + kg * 8;
            bh[nt] = *(const bf16x8*)(Bh + boff);
            bl[nt] = *(const bf16x8*)(Bl + boff);
        }
#pragma unroll
        for (int mt = 0; mt < MT; ++mt) {
            int ao = (mt * 16 + cn) * 40 + kg * 8;
            bf16x8 ah = *(const bf16x8*)(A_hi + ao);
            bf16x8 al = *(const bf16x8*)(A_lo + ao);
#pragma unroll
            for (int nt = 0; nt < NT; ++nt) {
                acc[mt][nt] = __builtin_amdgcn_mfma_f32_16x16x32_bf16(al, bh[nt], acc[mt][nt], 0, 0, 0);
                acc[mt][nt] = __builtin_amdgcn_mfma_f32_16x16x32_bf16(ah, bl[nt], acc[mt][nt], 0, 0, 0);
                acc[mt][nt] = __builtin_amdgcn_mfma_f32_16x16x32_bf16(ah, bh[nt], acc[mt][nt], 0, 0, 0);
            }
        }
        __syncthreads();
    }

    if (MODE == 0) {
        unsigned* gp = (unsigned*)outp;
        const int b = m0 >> 12;
#pragma unroll
        for (int nt = 0; nt < NT; ++nt) {
            int col = n0 + (w * NT + nt) * 16 + cn;
            float s = sv[col], bb = bvv[col];
            float mx = -1e30f;
#pragma unroll
            for (int mt = 0; mt < MT; ++mt)
#pragma unroll
                for (int r = 0; r < 4; ++r) mx = fmaxf(mx, lrelu(acc[mt][nt][r] * s + bb));
            mx = fmaxf(mx, __shfl_xor(mx, 16, 64));
            mx = fmaxf(mx, __shfl_xor(mx, 32, 64));
            if (kg == 0) atomicMax(&gp[b * NTOT + col], fenc(mx));
        }
    } else {
        float* of = (float*)outp;
        const int b = m0 >> 12;
        const int nrow0 = m0 & 4095;
        int col = w * 16 + cn;
        if (col < 63) {
            float bb = bvv[col];
#pragma unroll
            for (int mt = 0; mt < MT; ++mt) {
                float4 o4;
                o4.x = acc[mt][0][0] + bb; o4.y = acc[mt][0][1] + bb;
                o4.z = acc[mt][0][2] + bb; o4.w = acc[mt][0][3] + bb;
                *(float4*)(of + (size_t)(b * 63 + col) * N_PTS + nrow0 + mt * 16 + kg * 4) = o4;
            }
        }
    }
}

// ---------------- MODE 2-style GEMM (contiguous packed A), packed output via LDS transpose ----------------
template<int MODE, int MT, int NT, int KD, int NTOT>
__global__ __launch_bounds__(256) void gemm_mfma_t(
    const unsigned* __restrict__ A0,
    const short* __restrict__ Bh, const short* __restrict__ Bl,
    const float* __restrict__ sv, const float* __restrict__ bvv,
    const float* __restrict__ extra, unsigned* __restrict__ op)
{
    const int t = threadIdx.x;
    const int w = t >> 6, lane = t & 63;
    const int cn = lane & 15, kg = lane >> 4;
    const int m0 = blockIdx.x * (MT * 16);
    const int n0 = blockIdx.y * (NT * 64);

    __shared__ __align__(16) short Abuf2[2 * MT * 16 * 40 > 2 * 16 * 132 * 2 ? 2 * MT * 16 * 40 : 2 * 16 * 132 * 2];
    short* A_hi = Abuf2;
    short* A_lo = Abuf2 + MT * 16 * 40;

    f32x4 acc[MT][NT];
#pragma unroll
    for (int mt = 0; mt < MT; ++mt)
#pragma unroll
        for (int nt = 0; nt < NT; ++nt) acc[mt][nt] = (f32x4){0.f, 0.f, 0.f, 0.f};

    for (int kc = 0; kc < KD / 32; ++kc) {
        {
            const int kq = (t & 7) * 4;
            const int r0 = t >> 3;
#pragma unroll
            for (int rr = 0; rr < (MT * 16) / 32; ++rr) {
                int row = r0 + rr * 32;
                int gk = kc * 32 + kq;
                uint4 v = *(const uint4*)(A0 + (size_t)(m0 + row) * KD + gk);
                short4 h, l;
                h.x = (short)(v.x >> 16); l.x = (short)v.x;
                h.y = (short)(v.y >> 16); l.y = (short)v.y;
                h.z = (short)(v.z >> 16); l.z = (short)v.z;
                h.w = (short)(v.w >> 16); l.w = (short)v.w;
                *(short4*)(A_hi + row * 40 + kq) = h;
                *(short4*)(A_lo + row * 40 + kq) = l;
            }
        }
        __syncthreads();
        bf16x8 bh[NT], bl[NT];
#pragma unroll
        for (int nt = 0; nt < NT; ++nt) {
            int col = n0 + (w * NT + nt) * 16 + cn;
            int boff = col * KD + kc * 32 + kg * 8;
            bh[nt] = *(const bf16x8*)(Bh + boff);
            bl[nt] = *(const bf16x8*)(Bl + boff);
        }
#pragma unroll
        for (int mt = 0; mt < MT; ++mt) {
            int ao = (mt * 16 + cn) * 40 + kg * 8;
            bf16x8 ah = *(const bf16x8*)(A_hi + ao);
            bf16x8 al = *(const bf16x8*)(A_lo + ao);
#pragma unroll
            for (int nt = 0; nt < NT; ++nt) {
                acc[mt][nt] = __builtin_amdgcn_mfma_f32_16x16x32_bf16(al, bh[nt], acc[mt][nt], 0, 0, 0);
                acc[mt][nt] = __builtin_amdgcn_mfma_f32_16x16x32_bf16(ah, bl[nt], acc[mt][nt], 0, 0, 0);
                acc[mt][nt] = __builtin_amdgcn_mfma_f32_16x16x32_bf16(ah, bh[nt], acc[mt][nt], 0, 0, 0);
            }
        }
        __syncthreads();
    }

    unsigned* T = (unsigned*)Abuf2;
    const int b = m0 >> 12;
#pragma unroll
    for (int mt = 0; mt < MT; ++mt) {
#pragma unroll
        for (int nt = 0; nt < NT; ++nt) {
            int col = n0 + (w * NT + nt) * 16 + cn;
            float s = sv[col], bb = bvv[col];
            float cc = (MODE == 1) ? extra[b * 512 + col] : 0.0f;
#pragma unroll
            for (int r = 0; r < 4; ++r) {
                float v = lrelu((acc[mt][nt][r] + cc) * s + bb);
                T[(kg * 4 + r) * 132 + (w * NT + nt) * 16 + cn] = pack_trunc(v);
            }
        }
        __syncthreads();
        {
            int row = t >> 4, c0 = (t & 15) * 8;
            uint4 u0 = *(uint4*)(T + row * 132 + c0);
            uint4 u1 = *(uint4*)(T + row * 132 + c0 + 4);
            int grow = m0 + mt * 16 + row;
            *(uint4*)(op + (size_t)grow * NTOT + n0 + c0) = u0;
            *(uint4*)(op + (size_t)grow * NTOT + n0 + c0 + 4) = u1;
        }
        __syncthreads();
    }
}

// ---------------- MODE 1 GEMM (three packed x-arrays), +c7 epilogue, packed output ----------------
template<int MT, int NT, int KD, int NTOT>
__global__ __launch_bounds__(256) void gemm_mfma_c7(
    const unsigned* __restrict__ A0, const unsigned* __restrict__ A1, const unsigned* __restrict__ A2,
    const short* __restrict__ Bh, const short* __restrict__ Bl,
    const float* __restrict__ sv, const float* __restrict__ bvv,
    const float* __restrict__ extra, unsigned* __restrict__ op)
{
    const int t = threadIdx.x;
    const int w = t >> 6, lane = t & 63;
    const int cn = lane & 15, kg = lane >> 4;
    const int m0 = blockIdx.x * (MT * 16);
    const int n0 = blockIdx.y * (NT * 64);

    __shared__ __align__(16) short Abuf2[2 * MT * 16 * 40 > 2 * 16 * 132 * 2 ? 2 * MT * 16 * 40 : 2 * 16 * 132 * 2];
    short* A_hi = Abuf2;
    short* A_lo = Abuf2 + MT * 16 * 40;

    f32x4 acc[MT][NT];
#pragma unroll
    for (int mt = 0; mt < MT; ++mt)
#pragma unroll
        for (int nt = 0; nt < NT; ++nt) acc[mt][nt] = (f32x4){0.f, 0.f, 0.f, 0.f};

    for (int kc = 0; kc < KD / 32; ++kc) {
        {
            const int kq = (t & 7) * 4;
            const int r0 = t >> 3;
#pragma unroll
            for (int rr = 0; rr < (MT * 16) / 32; ++rr) {
                int row = r0 + rr * 32;
                int gk = kc * 32 + kq;
                const unsigned* srcp = (gk < 64) ? A0 : ((gk < 128) ? A1 : A2);
                uint4 v = *(const uint4*)(srcp + (size_t)(m0 + row) * 64 + (gk & 63));
                short4 h, l;
                h.x = (short)(v.x >> 16); l.x = (short)v.x;
                h.y = (short)(v.y >> 16); l.y = (short)v.y;
                h.z = (short)(v.z >> 16); l.z = (short)v.z;
                h.w = (short)(v.w >> 16); l.w = (short)v.w;
                *(short4*)(A_hi + row * 40 + kq) = h;
                *(short4*)(A_lo + row * 40 + kq) = l;
            }
        }
        __syncthreads();
        bf16x8 bh[NT], bl[NT];
#pragma unroll
        for (int nt = 0; nt < NT; ++nt) {
            int col = n0 + (w * NT + nt) * 16 + cn;
            int boff = col * KD + kc * 32 + kg * 8;
            bh[nt] = *(const bf16x8*)(Bh + boff);
            bl[nt] = *(const bf16x8*)(Bl + boff);
        }
#pragma unroll
        for (int mt = 0; mt < MT; ++mt) {
            int ao = (mt * 16 + cn) * 40 + kg * 8;
            bf16x8 ah = *(const bf16x8*)(A_hi + ao);
            bf16x8 al = *(const bf16x8*)(A_lo + ao);
#pragma unroll
            for (int nt = 0; nt < NT; ++nt) {
                acc[mt][nt] = __builtin_amdgcn_mfma_f32_16x16x32_bf16(al, bh[nt], acc[mt][nt], 0, 0, 0);
                acc[mt][nt] = __builtin_amdgcn_mfma_f32_16x16x32_bf16(ah, bl[nt], acc[mt][nt], 0, 0, 0);
                acc[mt][nt] = __builtin_amdgcn_mfma_f32_16x16x32_bf16(ah, bh[nt], acc[mt][nt], 0, 0, 0);
            }
        }
        __syncthreads();
    }

    unsigned* T = (unsigned*)Abuf2;
    const int b = m0 >> 12;
#pragma unroll
    for (int mt = 0; mt < MT; ++mt) {
#pragma unroll
        for (int nt = 0; nt < NT; ++nt) {
            int col = n0 + (w * NT + nt) * 16 + cn;
            float s = sv[col], bb = bvv[col];
            float cc = extra[b * 512 + col];
#pragma unroll
            for (int r = 0; r < 4; ++r) {
                float v = lrelu((acc[mt][nt][r] + cc) * s + bb);
                T[(kg * 4 + r) * 132 + (w * NT + nt) * 16 + cn] = pack_trunc(v);
            }
        }
        __syncthreads();
        {
            int row = t >> 4, c0 = (t & 15) * 8;
            uint4 u0 = *(uint4*)(T + row * 132 + c0);
            uint4 u1 = *(uint4*)(T + row * 132 + c0 + 4);
            int grow = m0 + mt * 16 + row;
            *(uint4*)(op + (size_t)grow * NTOT + n0 + c0) = u0;
            *(uint4*)(op + (size_t)grow * NTOT + n0 + c0 + 4) = u1;
        }
        __syncthreads();
    }
}

// c7 = W7[:, :1024] . g  — split-K x16 + 16-lane shuffle-reduce (128 blocks on the serial chain);
// g arrives fenc()-encoded from conv6's atomicMax epilogue, decode inline.
__global__ __launch_bounds__(256) void c7_kernel(const unsigned* __restrict__ g, const float* __restrict__ W7,
                                                 float* __restrict__ c7)
{
    int gid = blockIdx.x * 256 + threadIdx.x;   // 32768 = 2048 outputs x 16 k-chunks
    int oc = gid >> 4;          // 0..2047 : b*512 + o
    int kc = gid & 15;          // k-chunk of 64
    int b = oc >> 9, o = oc & 511;
    const unsigned* gb = g + b * 1024 + kc * 64;
    const float* wr = W7 + o * 1216 + kc * 64;
    float s = 0.0f;
#pragma unroll
    for (int i = 0; i < 64; i += 4) {
        float4 wv4 = *reinterpret_cast<const float4*>(&wr[i]);
        uint4  gv4 = *reinterpret_cast<const uint4*>(&gb[i]);
        s += wv4.x * fdec(gv4.x) + wv4.y * fdec(gv4.y)
           + wv4.z * fdec(gv4.z) + wv4.w * fdec(gv4.w);
    }
    s += __shfl_down(s, 8, 64);
    s += __shfl_down(s, 4, 64);
    s += __shfl_down(s, 2, 64);
    s += __shfl_down(s, 1, 64);
    if (kc == 0) c7[oc] = s;
}

extern "C" void kernel_launch(void* const* d_in, const int* in_sizes, int n_in,
                              void* d_out, int out_size, void* d_ws, size_t ws_size,
                              hipStream_t stream)
{
    const float* x  = (const float*)d_in[0];
    const float* W1 = (const float*)d_in[1];
    const float* s1 = (const float*)d_in[2];
    const float* b1 = (const float*)d_in[3];
    const float* W2 = (const float*)d_in[4];
    const float* s2 = (const float*)d_in[5];
    const float* b2 = (const float*)d_in[6];
    const float* W3 = (const float*)d_in[7];
    const float* s3 = (const float*)d_in[8];
    const float* b3 = (const float*)d_in[9];
    const float* W4 = (const float*)d_in[10];
    const float* s4 = (const float*)d_in[11];
    const float* b4 = (const float*)d_in[12];
    const float* W5 = (const float*)d_in[13];
    const float* s5 = (const float*)d_in[14];
    const float* b5 = (const float*)d_in[15];
    const float* W6 = (const float*)d_in[16];
    const float* s6 = (const float*)d_in[17];
    const float* b6 = (const float*)d_in[18];
    const float* W7 = (const float*)d_in[19];
    const float* s7 = (const float*)d_in[20];
    const float* b7 = (const float*)d_in[21];
    const float* W8 = (const float*)d_in[22];
    const float* s8 = (const float*)d_in[23];
    const float* b8 = (const float*)d_in[24];
    const float* W9 = (const float*)d_in[25];
    const float* b9 = (const float*)d_in[26];

    char* ws = (char*)d_ws;
    int*      idx   = (int*)(ws);                      // 2.62 MB
    unsigned* x1p   = (unsigned*)(ws + 15204352);
    unsigned* x2p   = (unsigned*)(ws + 19398656);
    unsigned* x3p   = (unsigned*)(ws + 23592960);
    unsigned* gu    = (unsigned*)(ws + 28311552);      // fenc-encoded global col-max (4096)
    float*    c7    = (float*)(ws + 28327936);
    short*    w3h   = (short*)(ws + 28336128);
    short*    w3l   = w3h + 4096;
    short*    w4h   = w3h + 8192;
    short*    w4l   = w3h + 12288;
    short*    w5h   = w3h + 16384;
    short*    w5l   = w3h + 20480;
    float*    wdt3  = (float*)(ws + 28385280);
    float*    wdt5  = (float*)(ws + 28401664);
    short*    w6h   = (short*)(ws + 28418048);
    short*    w6l   = (short*)(ws + 28811264);
    short*    w7h   = (short*)(ws + 29204480);
    short*    w7l   = (short*)(ws + 29401088);
    short*    w8h   = (short*)(ws + 29597696);
    short*    w8l   = (short*)(ws + 29859840);
    short*    w9h   = (short*)(ws + 30121984);
    short*    w9l   = (short*)(ws + 30154752);
    short*    w2h   = (short*)(ws + 30187520);
    short*    w2l   = (short*)(ws + 30195712);
    unsigned* h7p   = (unsigned*)(ws + 30408704);      // 33.55 MB -> ends 63963136
    unsigned* h8p   = (unsigned*)(ws);                 // aliases dead early buffers
    float*    outp  = (float*)d_out;

    knn_kernel<<<BATCH * N_PTS / 2, 256, 0, stream>>>(x, idx);
    prep_all<<<1728, 256, 0, stream>>>(W2, W3, W4, W5, W6, W7, W8, W9,
        w2h, w2l, w3h, w3l, w4h, w4l, w5h, w5l, wdt3, wdt5,
        w6h, w6l, w7h, w7l, w8h, w8l, w9h, w9l, gu);
    layer1_mfma_kernel<<<BATCH * N_PTS / 2, 256, 0, stream>>>(x, idx, W1, s1, b1, w2h, w2l, s2, b2, x1p);
    edge_mfma_kernel<1><<<BATCH * N_PTS / 2, 256, 0, stream>>>(x1p, idx, w3h, w3l, wdt3, s3, b3, w4h, w4l, s4, b4, x2p);
    edge_mfma_kernel<0><<<BATCH * N_PTS / 2, 256, 0, stream>>>(x2p, idx, w5h, w5l, wdt5, s5, b5, nullptr, nullptr, nullptr, nullptr, x3p);
    gemm_mfma<0, 8, 2, 192, 1024><<<dim3(128, 8), 256, 0, stream>>>(x1p, x2p, x3p, w6h, w6l, s6, b6, nullptr, gu);
    c7_kernel<<<128, 256, 0, stream>>>(gu, W7, c7);
    gemm_mfma_c7<8, 2, 192, 512><<<dim3(128, 4), 256, 0, stream>>>(x1p, x2p, x3p, w7h, w7l, s7, b7, c7, h7p);
    gemm_mfma_t<2, 4, 2, 512, 256><<<dim3(256, 2), 256, 0, stream>>>(h7p, w8h, w8l, s8, b8, nullptr, h8p);
    gemm_mfma<3, 4, 1, 256, 64><<<dim3(256, 1), 256, 0, stream>>>(h8p, nullptr, nullptr, w9h, w9l, nullptr, b9, nullptr, outp);
}